// Round 15
// baseline (487.356 us; speedup 1.0000x reference)
//
#include <hip/hip_runtime.h>
#include <hip/hip_bf16.h>

#define DIM 128
#define K 8
#define EPS 1e-8f
#define SQRT_EPS 1e-6f

#define CB 256           // clauses per fine bucket
#define CSHIFT 8
#define NBMAX 8192
#define MAXSLOT 32       // graph slots per bucket
#define SARR_CAP 1280    // mean 768, +18 sigma

// input tiles
#define TV1 4096
#define NT1MAX 2048
// v-level: 512 groups of 1024 vars
#define NKV 512
#define VSH 10
// attach/coarse-c level
#define TB 2048
#define MAXTV 8
#define NKC 64           // coarse clause groups (c>>15): 32768-clause segments
// fine-c level: 128 fine buckets (256 clauses) per coarse segment
#define TC 2048
#define MAXTC 64
#define NFB 128          // fine bins per coarse segment

typedef __attribute__((ext_vector_type(8))) short bf16x8;
typedef __attribute__((ext_vector_type(4))) float f32x4;

__device__ inline short bfc(float f) {
    union { __hip_bfloat16 h; short s; } u;
    u.h = __float2bfloat16(f);
    return u.s;
}

#define LDW 136
#define NW 8   // waves per mlp block

// ---------------- one-shot: transpose W1,W2 to bf16 in global ----------------
__global__ __launch_bounds__(512) void prep_kernel(
    const float* __restrict__ W1, const float* __restrict__ W2,
    unsigned short* __restrict__ w1tg, unsigned short* __restrict__ w2tg)
{
    const int t = threadIdx.x;
    for (int i = t; i < DIM * DIM; i += 512) {
        int r = i >> 7, c = i & 127;
        w1tg[c * DIM + r] = (unsigned short)bfc(W1[i]);
    }
    for (int i = t; i < 16 * DIM; i += 512) {
        int c = i >> 7, j = i & 127;
        w2tg[c * DIM + j] = (c < 8) ? (unsigned short)bfc(W2[j * 8 + c])
                                    : (unsigned short)0;
    }
}

// ---------------- MLP via MFMA: logits = relu(x@W1+b1)@W2+b2 -> fp8 ----------
__global__ __launch_bounds__(512) void mlp_kernel(
    const float* __restrict__ x, const unsigned short* __restrict__ w1tg,
    const float* __restrict__ b1, const unsigned short* __restrict__ w2tg,
    const float* __restrict__ b2, uint2* __restrict__ lfp8, int n_vars)
{
    __shared__ __align__(16) short w1t[DIM][LDW];       // 34816 B
    __shared__ __align__(16) short hlds[NW][16][LDW];   // 34816 B
    __shared__ __align__(16) float lout[NW][16][8];     //  4096 B

    const int t = threadIdx.x;
    const int wave = t >> 6, lane = t & 63;
    const int lr = lane & 15, lg = lane >> 4;

    for (int i = t; i < DIM * DIM / 8; i += 512) {
        int row = i >> 4, col8 = (i & 15) * 8;
        *(bf16x8*)&w1t[row][col8] = *(const bf16x8*)&w1tg[row * DIM + col8];
    }
    __syncthreads();

    const int rbase = blockIdx.x * 256 + wave * 32;

    bf16x8 a[2][4];
    #pragma unroll
    for (int rt = 0; rt < 2; ++rt) {
        int row = rbase + rt * 16 + lr;
        bool ok = row < n_vars;
        const float* xp = x + (size_t)row * DIM + lg * 8;
        #pragma unroll
        for (int kt = 0; kt < 4; ++kt) {
            bf16x8 av = {0,0,0,0,0,0,0,0};
            if (ok) {
                float4 f0 = *(const float4*)(xp + kt * 32);
                float4 f1 = *(const float4*)(xp + kt * 32 + 4);
                av[0]=bfc(f0.x); av[1]=bfc(f0.y); av[2]=bfc(f0.z); av[3]=bfc(f0.w);
                av[4]=bfc(f1.x); av[5]=bfc(f1.y); av[6]=bfc(f1.z); av[7]=bfc(f1.w);
            }
            a[rt][kt] = av;
        }
    }

    bf16x8 bb[4];
    #pragma unroll
    for (int kt = 0; kt < 4; ++kt)
        bb[kt] = *(const bf16x8*)&w2tg[lr * DIM + kt * 32 + lg * 8];
    float b2v = (lr < 8) ? b2[lr] : 0.f;

    #pragma unroll
    for (int rt = 0; rt < 2; ++rt) {
        #pragma unroll
        for (int n = 0; n < 8; ++n) {
            f32x4 acc = {0.f, 0.f, 0.f, 0.f};
            #pragma unroll
            for (int kt = 0; kt < 4; ++kt) {
                bf16x8 bf = *(const bf16x8*)&w1t[n * 16 + lr][kt * 32 + lg * 8];
                acc = __builtin_amdgcn_mfma_f32_16x16x32_bf16(a[rt][kt], bf, acc, 0, 0, 0);
            }
            float bcol = b1[n * 16 + lr];
            #pragma unroll
            for (int r = 0; r < 4; ++r) {
                float h = fmaxf(acc[r] + bcol, 0.f);
                hlds[wave][lg * 4 + r][n * 16 + lr] = bfc(h);
            }
        }
        f32x4 acc2 = {0.f, 0.f, 0.f, 0.f};
        #pragma unroll
        for (int kt = 0; kt < 4; ++kt) {
            bf16x8 af = *(const bf16x8*)&hlds[wave][lr][kt * 32 + lg * 8];
            acc2 = __builtin_amdgcn_mfma_f32_16x16x32_bf16(af, bb[kt], acc2, 0, 0, 0);
        }
        if (lr < 8) {
            #pragma unroll
            for (int r = 0; r < 4; ++r)
                lout[wave][lg * 4 + r][lr] = acc2[r] + b2v;
        }
        if (lane < 16) {
            int row = rbase + rt * 16 + lane;
            if (row < n_vars) {
                const float* f = lout[wave][lane];
                unsigned lo = 0u, hi = 0u;
                lo = __builtin_amdgcn_cvt_pk_fp8_f32(f[0], f[1], lo, false);
                lo = __builtin_amdgcn_cvt_pk_fp8_f32(f[2], f[3], lo, true);
                hi = __builtin_amdgcn_cvt_pk_fp8_f32(f[4], f[5], hi, false);
                hi = __builtin_amdgcn_cvt_pk_fp8_f32(f[6], f[7], hi, true);
                lfp8[row] = make_uint2(lo, hi);
            }
        }
    }
}

// ================= level V: partition by variable group ======================

__global__ __launch_bounds__(256) void histV_kernel(
    const int* __restrict__ vi, unsigned* __restrict__ histV, int n_edges)
{
    __shared__ unsigned hl[NKV];
    const int t = threadIdx.x, b = blockIdx.x;
    for (int i = t; i < NKV; i += 256) hl[i] = 0u;
    __syncthreads();
    const int e0 = b * TV1, e1 = min(e0 + TV1, n_edges);
    for (int e = e0 + t; e < e1; e += 256)
        atomicAdd(&hl[((unsigned)vi[e]) >> VSH], 1u);
    __syncthreads();
    for (int i = t; i < NKV; i += 256) histV[(size_t)i * NT1MAX + b] = hl[i];
}

// exclusive scan each row (width NT1MAX=2048) over tiles: 8 elems/thread
__global__ __launch_bounds__(256) void scanrowV_kernel(
    unsigned* __restrict__ hist, unsigned* __restrict__ btotal)
{
    const int t = threadIdx.x;
    const size_t base = (size_t)blockIdx.x * NT1MAX + t * 8;
    uint4 v0 = *(const uint4*)(hist + base);
    uint4 v1 = *(const uint4*)(hist + base + 4);
    unsigned p0 = 0, p1 = v0.x, p2 = p1 + v0.y, p3 = p2 + v0.z, p4 = p3 + v0.w;
    unsigned p5 = p4 + v1.x, p6 = p5 + v1.y, p7 = p6 + v1.z;
    unsigned run = p7 + v1.w;
    __shared__ unsigned ts[256];
    ts[t] = run;
    __syncthreads();
    for (int off = 1; off < 256; off <<= 1) {
        unsigned xv = (t >= off) ? ts[t - off] : 0u;
        __syncthreads();
        ts[t] += xv;
        __syncthreads();
    }
    unsigned ex = ts[t] - run;
    uint4 o0 = {ex + p0, ex + p1, ex + p2, ex + p3};
    uint4 o1 = {ex + p4, ex + p5, ex + p6, ex + p7};
    *(uint4*)(hist + base) = o0;
    *(uint4*)(hist + base + 4) = o1;
    if (t == 255) btotal[blockIdx.x] = ts[255];
}

__global__ void baseV_kernel(const unsigned* __restrict__ tv,
                             unsigned* __restrict__ bv)
{
    if (threadIdx.x == 0) {
        unsigned r = 0;
        for (int k = 0; k < NKV; ++k) { bv[k] = r; r += tv[k]; }
        bv[NKV] = r;
    }
}

// staged scatter into v-group order; payload u32 = voff<<22 | neg<<21 | c
__global__ __launch_bounds__(256) void scatterV_kernel(
    const int* __restrict__ ci, const int* __restrict__ vi,
    const float* __restrict__ pol, const unsigned* __restrict__ histV,
    const unsigned* __restrict__ baseV, unsigned* __restrict__ A, int n_edges)
{
    __shared__ unsigned sa[TV1];            // 16 KB
    __shared__ unsigned short bmap[TV1];    //  8 KB
    __shared__ unsigned h[NKV], lst[NKV], h2[NKV], gst[NKV];  // 8 KB
    __shared__ unsigned ts[256];
    const int t = threadIdx.x, b = blockIdx.x;
    for (int i = t; i < NKV; i += 256) h[i] = 0u;
    __syncthreads();
    const int e0 = b * TV1, e1 = min(e0 + TV1, n_edges), n = e1 - e0;
    for (int e = e0 + t; e < e1; e += 256)
        atomicAdd(&h[((unsigned)vi[e]) >> VSH], 1u);
    __syncthreads();
    unsigned a0 = h[2 * t], a1 = h[2 * t + 1];
    unsigned run = a0 + a1;
    ts[t] = run;
    __syncthreads();
    for (int off = 1; off < 256; off <<= 1) {
        unsigned xv = (t >= off) ? ts[t - off] : 0u;
        __syncthreads();
        ts[t] += xv;
        __syncthreads();
    }
    unsigned ex = ts[t] - run;
    lst[2 * t] = ex; lst[2 * t + 1] = ex + a0;
    h2[2 * t] = ex;  h2[2 * t + 1] = ex + a0;
    __syncthreads();
    for (int e = e0 + t; e < e1; e += 256) {
        unsigned c = (unsigned)ci[e];
        unsigned v = (unsigned)vi[e];
        unsigned neg = (pol[e] < 0.f) ? 1u : 0u;
        unsigned k = v >> VSH;
        unsigned p = atomicAdd(&h2[k], 1u);
        sa[p] = c | (neg << 21) | ((v & ((1u << VSH) - 1u)) << 22);
        bmap[p] = (unsigned short)k;
    }
    for (int i = t; i < NKV; i += 256)
        gst[i] = baseV[i] + histV[(size_t)i * NT1MAX + b];
    __syncthreads();
    for (int s = t; s < n; s += 256) {
        unsigned k = bmap[s];
        A[gst[k] + (s - lst[k])] = sa[s];
    }
}

// ================= level B: attach sign-applied logits + coarse-c partition ==

__global__ __launch_bounds__(256) void histB_kernel(
    const unsigned* __restrict__ A, const unsigned* __restrict__ baseV,
    unsigned* __restrict__ histB)
{
    __shared__ unsigned h[NKC];
    const int t = threadIdx.x;
    const int vg = blockIdx.x / MAXTV, i = blockIdx.x % MAXTV;
    const unsigned slo = baseV[vg], shi = baseV[vg + 1];
    const unsigned t0 = slo + (unsigned)i * TB;
    if (t0 >= shi) return;
    const unsigned t1 = min(t0 + TB, shi);
    if (t < NKC) h[t] = 0u;
    __syncthreads();
    for (unsigned e = t0 + t; e < t1; e += 256)
        atomicAdd(&h[(A[e] & 0x1FFFFFu) >> 15], 1u);
    __syncthreads();
    if (t < NKC) histB[(size_t)t * (NKV * MAXTV) + blockIdx.x] = h[t];
}

// exclusive scan each row (width NKV*MAXTV = 4096): 16 elems/thread
__global__ __launch_bounds__(256) void scanrowB_kernel(
    unsigned* __restrict__ hist, unsigned* __restrict__ btotal)
{
    const int t = threadIdx.x;
    const size_t base = (size_t)blockIdx.x * (NKV * MAXTV) + t * 16;
    unsigned v[16];
    #pragma unroll
    for (int q = 0; q < 4; ++q) {
        uint4 vv = *(const uint4*)(hist + base + q * 4);
        v[q*4+0]=vv.x; v[q*4+1]=vv.y; v[q*4+2]=vv.z; v[q*4+3]=vv.w;
    }
    unsigned pre[16];
    unsigned run = 0;
    #pragma unroll
    for (int q = 0; q < 16; ++q) { pre[q] = run; run += v[q]; }
    __shared__ unsigned ts[256];
    ts[t] = run;
    __syncthreads();
    for (int off = 1; off < 256; off <<= 1) {
        unsigned xv = (t >= off) ? ts[t - off] : 0u;
        __syncthreads();
        ts[t] += xv;
        __syncthreads();
    }
    unsigned ex = ts[t] - run;
    #pragma unroll
    for (int q = 0; q < 4; ++q) {
        uint4 o = {ex + pre[q*4+0], ex + pre[q*4+1], ex + pre[q*4+2], ex + pre[q*4+3]};
        *(uint4*)(hist + base + q * 4) = o;
    }
    if (t == 255) btotal[blockIdx.x] = ts[255];
}

__global__ void baseB_kernel(const unsigned* __restrict__ tb,
                             unsigned* __restrict__ bb)
{
    if (threadIdx.x == 0) {
        unsigned r = 0;
        for (int k = 0; k < NKC; ++k) { bb[k] = r; r += tb[k]; }
        bb[NKC] = r;
    }
}

// attach: LDS logit slice + SIGN-APPLY (e4m3 negation = flip bit7) + scatter
__global__ __launch_bounds__(256) void scatterB_kernel(
    const unsigned* __restrict__ A, const uint2* __restrict__ lfp8,
    const unsigned* __restrict__ baseV, const unsigned* __restrict__ histB,
    const unsigned* __restrict__ baseB, unsigned short* __restrict__ B1,
    uint2* __restrict__ B2, int n_vars)
{
    __shared__ uint2 slice[1 << VSH];       //  8 KB
    __shared__ unsigned short st1[TB];      //  4 KB
    __shared__ uint2 st2[TB];               // 16 KB
    __shared__ unsigned char bmap[TB];      //  2 KB
    __shared__ unsigned h[NKC], lst[NKC], h2[NKC], gst[NKC];
    const int t = threadIdx.x;
    const int vg = blockIdx.x / MAXTV, i = blockIdx.x % MAXTV;
    const unsigned slo = baseV[vg], shi = baseV[vg + 1];
    const unsigned t0 = slo + (unsigned)i * TB;
    if (t0 >= shi) return;
    const unsigned t1 = min(t0 + TB, shi);
    const int n = (int)(t1 - t0);
    for (int s = t; s < (1 << VSH); s += 256) {
        int v = (vg << VSH) + s;
        slice[s] = (v < n_vars) ? lfp8[v] : make_uint2(0u, 0u);
    }
    if (t < NKC) h[t] = 0u;
    __syncthreads();
    for (unsigned e = t0 + t; e < t1; e += 256)
        atomicAdd(&h[(A[e] & 0x1FFFFFu) >> 15], 1u);
    __syncthreads();
    if (t == 0) {
        unsigned r = 0;
        for (int k = 0; k < NKC; ++k) { lst[k] = r; h2[k] = r; r += h[k]; }
    }
    __syncthreads();
    for (unsigned e = t0 + t; e < t1; e += 256) {
        unsigned a = A[e];
        unsigned c = a & 0x1FFFFFu;
        unsigned k = c >> 15;
        unsigned p = atomicAdd(&h2[k], 1u);
        uint2 g = slice[a >> 22];
        unsigned sm = ((a >> 21) & 1u) * 0x80808080u;  // negation = sign-bit flip
        g.x ^= sm; g.y ^= sm;
        st1[p] = (unsigned short)(c & 0x7FFFu);
        st2[p] = g;
        bmap[p] = (unsigned char)k;
    }
    if (t < NKC) gst[t] = baseB[t] + histB[(size_t)t * (NKV * MAXTV) + blockIdx.x];
    __syncthreads();
    for (int s = t; s < n; s += 256) {
        unsigned k = bmap[s];
        unsigned pos = gst[k] + (s - lst[k]);
        B1[pos] = st1[s];
        B2[pos] = st2[s];
    }
}

// ================= level C: fine clause-bucket scatter (128 bins) ============

__global__ __launch_bounds__(256) void histC_kernel(
    const unsigned short* __restrict__ B1, const unsigned* __restrict__ baseB,
    unsigned* __restrict__ histC)
{
    __shared__ unsigned h[NFB];
    const int t = threadIdx.x;
    const int k1 = blockIdx.x / MAXTC, i = blockIdx.x % MAXTC;
    const unsigned slo = baseB[k1], shi = baseB[k1 + 1];
    const unsigned t0 = slo + (unsigned)i * TC;
    if (t0 >= shi) return;
    const unsigned t1 = min(t0 + TC, shi);
    if (t < NFB) h[t] = 0u;
    __syncthreads();
    for (unsigned e = t0 + t; e < t1; e += 256)
        atomicAdd(&h[((unsigned)B1[e] >> CSHIFT) & (NFB - 1u)], 1u);
    __syncthreads();
    if (t < NFB) histC[(size_t)(k1 * NFB + t) * MAXTC + i] = h[t];
}

__global__ __launch_bounds__(256) void scanrowC_kernel(
    unsigned* __restrict__ histC, unsigned* __restrict__ ctotal)
{
    const int rid = blockIdx.x * 256 + threadIdx.x;   // 0..8191 == fine bucket
    unsigned r = 0;
    for (int i = 0; i < MAXTC; ++i) {
        unsigned v = histC[(size_t)rid * MAXTC + i];
        histC[(size_t)rid * MAXTC + i] = r;
        r += v;
    }
    ctotal[rid] = r;
}

__global__ __launch_bounds__(256) void bbase_kernel(
    const unsigned* __restrict__ ctotal, unsigned* __restrict__ bbase, int nb)
{
    const int t = threadIdx.x;
    unsigned loc[32];
    unsigned run = 0;
    #pragma unroll
    for (int it = 0; it < 32; ++it) {
        int idx = t * 32 + it;
        unsigned v = (idx < 8192) ? ctotal[idx] : 0u;
        loc[it] = run;
        run += v;
    }
    __shared__ unsigned ts[256];
    ts[t] = run;
    __syncthreads();
    for (int off = 1; off < 256; off <<= 1) {
        unsigned xv = (t >= off) ? ts[t - off] : 0u;
        __syncthreads();
        ts[t] += xv;
        __syncthreads();
    }
    unsigned ex = ts[t] - run;
    #pragma unroll
    for (int it = 0; it < 32; ++it) {
        int idx = t * 32 + it;
        if (idx <= nb) bbase[idx] = ex + loc[it];
    }
}

__global__ __launch_bounds__(256) void scatterC_kernel(
    const unsigned short* __restrict__ B1, const uint2* __restrict__ B2,
    const unsigned* __restrict__ baseB, const unsigned* __restrict__ histC,
    const unsigned* __restrict__ bbase, unsigned short* __restrict__ sortedS,
    uint2* __restrict__ sortedL)
{
    __shared__ unsigned short st1[TC];      //  4 KB
    __shared__ uint2 st2[TC];               // 16 KB
    __shared__ unsigned char bmap[TC];      //  2 KB
    __shared__ unsigned h[NFB], lst[NFB], h2[NFB], gst[NFB];  // 2 KB
    const int t = threadIdx.x;
    const int k1 = blockIdx.x / MAXTC, i = blockIdx.x % MAXTC;
    const unsigned slo = baseB[k1], shi = baseB[k1 + 1];
    const unsigned t0 = slo + (unsigned)i * TC;
    if (t0 >= shi) return;
    const unsigned t1 = min(t0 + TC, shi);
    const int n = (int)(t1 - t0);
    if (t < NFB) h[t] = 0u;
    __syncthreads();
    for (unsigned e = t0 + t; e < t1; e += 256)
        atomicAdd(&h[((unsigned)B1[e] >> CSHIFT) & (NFB - 1u)], 1u);
    __syncthreads();
    if (t == 0) {
        unsigned r = 0;
        for (int k = 0; k < NFB; ++k) { lst[k] = r; h2[k] = r; r += h[k]; }
    }
    __syncthreads();
    for (unsigned e = t0 + t; e < t1; e += 256) {
        unsigned b = (unsigned)B1[e];
        unsigned k2 = (b >> CSHIFT) & (NFB - 1u);
        unsigned p = atomicAdd(&h2[k2], 1u);
        st1[p] = (unsigned short)(b & (CB - 1u));
        st2[p] = B2[e];
        bmap[p] = (unsigned char)k2;
    }
    if (t < NFB) {
        unsigned cbk = (unsigned)(k1 * NFB + t);
        gst[t] = bbase[cbk] + histC[(size_t)cbk * MAXTC + i];
    }
    __syncthreads();
    for (int s = t; s < n; s += 256) {
        unsigned k = bmap[s];
        unsigned pos = gst[k] + (s - lst[k]);
        sortedS[pos] = st1[s];
        sortedL[pos] = st2[s];
    }
}

// ------- bucket: counting-sort + owner-reduce (1 clause/thread) --------------
__global__ __launch_bounds__(256) void bucket_kernel(
    const unsigned short* __restrict__ sortedS, const uint2* __restrict__ sortedL,
    const unsigned* __restrict__ bbase, const int* __restrict__ clause_batch,
    float* __restrict__ per_graph, unsigned* __restrict__ gmask,
    int n_clauses, int n_graphs)
{
    __shared__ uint2 sarrL[SARR_CAP];   // 10.2 KB (aliased as acc in fallback)
    __shared__ unsigned cnt[CB];        //  1 KB (count -> cursor)
    __shared__ unsigned cst[CB + 1];    //  1 KB
    __shared__ float sp[256];           //  1 KB
    __shared__ float pg[MAXSLOT * K];   //  1 KB
    __shared__ unsigned pmask[MAXSLOT];
    __shared__ unsigned wtot[4];
    __shared__ int sh_ghi;

    const int t = threadIdx.x;
    const int lane = t & 63, wv = t >> 6;
    const int bkt = blockIdx.x;
    const int c_base = bkt << CSHIFT;
    const int n_cl = min(CB, n_clauses - c_base);
    const int g_lo = clause_batch[c_base];

    {
        float v = __builtin_amdgcn_cvt_f32_fp8((unsigned)t, 0);
        sp[t] = fmaxf(v, 0.f) + __logf(1.f + __expf(-fabsf(v)));
    }
    cnt[t] = 0u;
    if (t < MAXSLOT) { pmask[t] = 0xFFu; }
    for (int i = t; i < MAXSLOT * K; i += 256) pg[i] = 0.f;
    if (t == 0) sh_ghi = clause_batch[c_base + n_cl - 1];
    __syncthreads();

    const unsigned lo = bbase[bkt], hi = bbase[bkt + 1];
    const int ne = (int)(hi - lo);

    float loss0[K];
    unsigned msk0 = 0u;
    bool have0 = false;

    if (ne <= SARR_CAP) {
        for (unsigned e = lo + t; e < hi; e += 256)
            atomicAdd(&cnt[sortedS[e] & (CB - 1u)], 1u);
        __syncthreads();
        unsigned a0 = cnt[t];
        unsigned incl = a0;
        #pragma unroll
        for (int off = 1; off < 64; off <<= 1) {
            unsigned v = __shfl_up(incl, off, 64);
            if (lane >= off) incl += v;
        }
        if (lane == 63) wtot[wv] = incl;
        __syncthreads();
        unsigned wpre = 0;
        #pragma unroll
        for (int w = 0; w < 3; ++w) if (w < wv) wpre += wtot[w];
        unsigned ex = wpre + incl - a0;
        cst[t] = ex;
        cnt[t] = ex;                       // cursor
        if (t == 255) cst[CB] = ex + a0;
        __syncthreads();
        for (unsigned e = lo + t; e < hi; e += 256) {
            unsigned cl = sortedS[e] & (CB - 1u);
            unsigned p = atomicAdd(&cnt[cl], 1u);
            sarrL[p] = sortedL[e];
        }
        __syncthreads();
        if (t < n_cl) {
            unsigned s0 = cst[t];
            int n = (int)(cst[t + 1] - s0);
            float sums[K] = {0.f, 0.f, 0.f, 0.f, 0.f, 0.f, 0.f, 0.f};
            unsigned ormask = 0u;
            for (int base = 0; base < n; base += 8) {
                int m = min(8, n - base);
                uint2 gs[8];
                for (int i2 = 0; i2 < m; ++i2) gs[i2] = sarrL[s0 + base + i2];
                for (int i2 = 0; i2 < m; ++i2) {
                    #pragma unroll
                    for (int j = 0; j < 4; ++j) {
                        unsigned b0 = (gs[i2].x >> (8 * j)) & 0xFFu;
                        unsigned b1 = (gs[i2].y >> (8 * j)) & 0xFFu;
                        sums[j]     += sp[b0];
                        sums[j + 4] += sp[b1];
                        ormask |= (b0 - 1u < 0x7Fu) ? (1u << j) : 0u;
                        ormask |= (b1 - 1u < 0x7Fu) ? (1u << (j + 4)) : 0u;
                    }
                }
            }
            #pragma unroll
            for (int j = 0; j < K; ++j) {
                float cv = __expf(-sums[j]);
                loss0[j] = cv * (-__logf(1.f - cv + EPS));
            }
            msk0 = ormask;
            have0 = true;
        }
    } else {
        float* acc = (float*)sarrL;        // 8 KB alias
        __shared__ unsigned fmsk[CB];
        for (int i = t; i < CB * K; i += 256) acc[i] = 0.f;
        fmsk[t] = 0u;
        __syncthreads();
        for (unsigned e = lo + t; e < hi; e += 256) {
            unsigned cl = sortedS[e] & (CB - 1u);
            uint2 g = sortedL[e];
            unsigned gt0 = 0u;
            #pragma unroll
            for (int j = 0; j < 4; ++j) {
                unsigned b0 = (g.x >> (8 * j)) & 0xFFu;
                unsigned b1 = (g.y >> (8 * j)) & 0xFFu;
                atomicAdd(&acc[cl * K + j], sp[b0]);
                atomicAdd(&acc[cl * K + j + 4], sp[b1]);
                gt0 |= (b0 - 1u < 0x7Fu) ? (1u << j) : 0u;
                gt0 |= (b1 - 1u < 0x7Fu) ? (1u << (j + 4)) : 0u;
            }
            atomicOr(&fmsk[cl], gt0);
        }
        __syncthreads();
        if (t < n_cl) {
            #pragma unroll
            for (int j = 0; j < K; ++j) {
                float cv = __expf(-acc[t * K + j]);
                loss0[j] = cv * (-__logf(1.f - cv + EPS));
            }
            msk0 = fmsk[t];
            have0 = true;
        }
    }

    // fused clause -> graph fold
    if (have0) {
        int slot0 = clause_batch[c_base + t] - g_lo;
        if (slot0 < MAXSLOT) {
            #pragma unroll
            for (int j = 0; j < K; ++j) atomicAdd(&pg[slot0 * K + j], loss0[j]);
            atomicAnd(&pmask[slot0], msk0);
        } else {
            #pragma unroll
            for (int j = 0; j < K; ++j) atomicAdd(&per_graph[(size_t)(g_lo + slot0) * K + j], loss0[j]);
            atomicAnd(&gmask[g_lo + slot0], msk0);
        }
    }
    __syncthreads();

    const int nslots = min(sh_ghi - g_lo + 1, MAXSLOT);
    if (t < nslots * K) {
        int s = t >> 3, j = t & 7;
        atomicAdd(&per_graph[(size_t)(g_lo + s) * K + j], pg[s * K + j]);
    }
    if (t < nslots) atomicAnd(&gmask[g_lo + t], pmask[t]);
}

// ---------------- Final: per-graph sqrt, sort-8, cost dot, solved ------------
__global__ __launch_bounds__(256) void final_kernel(
    const float* __restrict__ per_graph, const unsigned* __restrict__ gmask,
    int n_graphs, float* __restrict__ out)
{
    const int t = threadIdx.x;
    float dot = 0.f;
    if (t < n_graphs) {
        float v[K];
        #pragma unroll
        for (int j = 0; j < K; ++j)
            v[j] = sqrtf(per_graph[(size_t)t * K + j] + SQRT_EPS) - sqrtf(SQRT_EPS);
        #pragma unroll
        for (int i = 1; i < K; ++i) {
            float key = v[i];
            int j = i - 1;
            while (j >= 0 && v[j] < key) { v[j + 1] = v[j]; --j; }
            v[j + 1] = key;
        }
        #pragma unroll
        for (int i = 0; i < K; ++i)
            dot = fmaf(v[i], (float)((i + 1) * (i + 1)), dot);
        out[1 + t] = (gmask[t] & 0xFFu) ? 1.f : 0.f;
    }
    __shared__ float red[256];
    red[t] = dot;
    __syncthreads();
    for (int s = 128; s >= 1; s >>= 1) {
        if (t < s) red[t] += red[t + s];
        __syncthreads();
    }
    if (t == 0) out[0] = red[0] * (1.f / 204.f);
}

// ---------------------------------------------------------------------------
extern "C" void kernel_launch(void* const* d_in, const int* in_sizes, int n_in,
                              void* d_out, int out_size, void* d_ws, size_t ws_size,
                              hipStream_t stream) {
    const float* x   = (const float*)d_in[0];
    const float* pol = (const float*)d_in[1];
    const int* vi    = (const int*)d_in[2];
    const int* ci    = (const int*)d_in[3];
    const int* cb    = (const int*)d_in[4];
    const float* W1  = (const float*)d_in[5];
    const float* b1  = (const float*)d_in[6];
    const float* W2  = (const float*)d_in[7];
    const float* b2  = (const float*)d_in[8];

    const int n_vars    = in_sizes[0] / DIM;
    const int n_edges   = in_sizes[1];
    const int n_clauses = in_sizes[4];
    const int n_graphs  = out_size - 1;
    const int nb        = (n_clauses + CB - 1) / CB;
    const int nt1       = (n_edges + TV1 - 1) / TV1;

    // ---- workspace layout ----
    char* ws = (char*)d_ws;
    size_t off = 0;
    auto alloc = [&](size_t bytes) { char* p = ws + off; off += (bytes + 255) & ~(size_t)255; return p; };
    uint2*    lfp8   = (uint2*)alloc((size_t)n_vars * 8);
    unsigned* A      = (unsigned*)alloc((size_t)n_edges * 4);
    unsigned short* B1 = (unsigned short*)alloc((size_t)n_edges * 2);
    uint2*    B2     = (uint2*)alloc((size_t)n_edges * 8);
    uint2*    sortedL= (uint2*)alloc((size_t)n_edges * 8);
    unsigned* histV  = (unsigned*)alloc((size_t)NKV * NT1MAX * 4);           // 4 MB
    unsigned* histB  = (unsigned*)alloc((size_t)NKC * NKV * MAXTV * 4);      // 1 MB
    unsigned* histC  = (unsigned*)alloc((size_t)8192 * MAXTC * 4);           // 2 MB
    unsigned* btotalV= (unsigned*)alloc((size_t)(NKV + 1) * 4);
    unsigned* baseV  = (unsigned*)alloc((size_t)(NKV + 1) * 4);
    unsigned* btotalB= (unsigned*)alloc((size_t)(NKC + 1) * 4);
    unsigned* baseB  = (unsigned*)alloc((size_t)(NKC + 1) * 4);
    unsigned* ctotal = (unsigned*)alloc((size_t)8192 * 4);
    unsigned* bbase  = (unsigned*)alloc((size_t)(NBMAX + 1) * 4);
    float*    per_graph = (float*)alloc((size_t)n_graphs * K * 4);
    unsigned* gmask  = (unsigned*)alloc((size_t)n_graphs * 4);
    unsigned short* w1tg = (unsigned short*)alloc((size_t)DIM * DIM * 2);
    unsigned short* w2tg = (unsigned short*)alloc((size_t)16 * DIM * 2);
    unsigned short* sortedS = (unsigned short*)A;   // alias: A dead after scatterB

    hipMemsetAsync(histV, 0, (size_t)NKV * NT1MAX * 4, stream);
    hipMemsetAsync(histB, 0, (size_t)NKC * NKV * MAXTV * 4, stream);
    hipMemsetAsync(histC, 0, (size_t)8192 * MAXTC * 4, stream);
    hipMemsetAsync(per_graph, 0, (size_t)n_graphs * K * 4, stream);
    hipMemsetAsync(gmask, 0xFF, (size_t)n_graphs * 4, stream);

    prep_kernel<<<1, 512, 0, stream>>>(W1, W2, w1tg, w2tg);
    mlp_kernel<<<(n_vars + 255) / 256, 512, 0, stream>>>(x, w1tg, b1, w2tg, b2,
                                                         lfp8, n_vars);

    histV_kernel<<<nt1, 256, 0, stream>>>(vi, histV, n_edges);
    scanrowV_kernel<<<NKV, 256, 0, stream>>>(histV, btotalV);
    baseV_kernel<<<1, 64, 0, stream>>>(btotalV, baseV);
    scatterV_kernel<<<nt1, 256, 0, stream>>>(ci, vi, pol, histV, baseV, A, n_edges);

    histB_kernel<<<NKV * MAXTV, 256, 0, stream>>>(A, baseV, histB);
    scanrowB_kernel<<<NKC, 256, 0, stream>>>(histB, btotalB);
    baseB_kernel<<<1, 64, 0, stream>>>(btotalB, baseB);
    scatterB_kernel<<<NKV * MAXTV, 256, 0, stream>>>(A, lfp8, baseV, histB, baseB,
                                                     B1, B2, n_vars);

    histC_kernel<<<NKC * MAXTC, 256, 0, stream>>>(B1, baseB, histC);
    scanrowC_kernel<<<32, 256, 0, stream>>>(histC, ctotal);
    bbase_kernel<<<1, 256, 0, stream>>>(ctotal, bbase, nb);
    scatterC_kernel<<<NKC * MAXTC, 256, 0, stream>>>(B1, B2, baseB, histC, bbase,
                                                     sortedS, sortedL);

    bucket_kernel<<<nb, 256, 0, stream>>>(sortedS, sortedL, bbase, cb,
                                          per_graph, gmask, n_clauses, n_graphs);
    final_kernel<<<1, 256, 0, stream>>>(per_graph, gmask, n_graphs, (float*)d_out);
}

// Round 16
// 453.038 us; speedup vs baseline: 1.0758x; 1.0758x over previous
//
#include <hip/hip_runtime.h>
#include <hip/hip_bf16.h>

#define DIM 128
#define K 8
#define EPS 1e-8f
#define SQRT_EPS 1e-6f

#define CB 512           // clauses per fine bucket
#define CSHIFT 9
#define NBMAX 4096
#define MAXSLOT 32       // graph slots per bucket
#define SARR_CAP 2560    // mean 1536, +26 sigma
#define MAXE 10          // SARR_CAP/256 register-staged edges per thread

// input tiles
#define TV1 8192
#define NT1MAX 1024
// v-level: 512 groups of 1024 vars
#define NKV 512
#define VSH 10
// attach/coarse-c level
#define TB 4096
#define MAXTV 4
#define NKC 64           // coarse clause groups (c>>15)
// fine-c level
#define TC 4096
#define MAXTC 32

typedef __attribute__((ext_vector_type(8))) short bf16x8;
typedef __attribute__((ext_vector_type(4))) float f32x4;

__device__ inline short bfc(float f) {
    union { __hip_bfloat16 h; short s; } u;
    u.h = __float2bfloat16(f);
    return u.s;
}

#define LDW 136
#define NW 8   // waves per mlp block

// ---------------- one-shot: transpose W1,W2 to bf16 in global ----------------
__global__ __launch_bounds__(512) void prep_kernel(
    const float* __restrict__ W1, const float* __restrict__ W2,
    unsigned short* __restrict__ w1tg, unsigned short* __restrict__ w2tg)
{
    const int t = threadIdx.x;
    for (int i = t; i < DIM * DIM; i += 512) {
        int r = i >> 7, c = i & 127;
        w1tg[c * DIM + r] = (unsigned short)bfc(W1[i]);
    }
    for (int i = t; i < 16 * DIM; i += 512) {
        int c = i >> 7, j = i & 127;
        w2tg[c * DIM + j] = (c < 8) ? (unsigned short)bfc(W2[j * 8 + c])
                                    : (unsigned short)0;
    }
}

// -------- fused: MLP (blocks < mlpB) || histV (blocks >= mlpB) ---------------
__global__ __launch_bounds__(512) void mlp_histV_kernel(
    const float* __restrict__ x, const unsigned short* __restrict__ w1tg,
    const float* __restrict__ b1, const unsigned short* __restrict__ w2tg,
    const float* __restrict__ b2, uint2* __restrict__ lfp8, int n_vars,
    const int* __restrict__ vi, unsigned* __restrict__ histV, int n_edges,
    int mlpB)
{
    __shared__ __align__(16) short w1t[DIM][LDW];       // 34816 B
    __shared__ __align__(16) short hlds[NW][16][LDW];   // 34816 B
    __shared__ __align__(16) float lout[NW][16][8];     //  4096 B
    __shared__ unsigned hl[NKV];                        //  2048 B

    const int t = threadIdx.x;

    if ((int)blockIdx.x >= mlpB) {
        // ---- histV role ----
        const int b = (int)blockIdx.x - mlpB;
        for (int i = t; i < NKV; i += 512) hl[i] = 0u;
        __syncthreads();
        const int e0 = b * TV1, e1 = min(e0 + TV1, n_edges);
        for (int e = e0 + t; e < e1; e += 512)
            atomicAdd(&hl[((unsigned)vi[e]) >> VSH], 1u);
        __syncthreads();
        for (int i = t; i < NKV; i += 512) histV[(size_t)i * NT1MAX + b] = hl[i];
        return;
    }

    // ---- MLP role ----
    const int wave = t >> 6, lane = t & 63;
    const int lr = lane & 15, lg = lane >> 4;

    for (int i = t; i < DIM * DIM / 8; i += 512) {
        int row = i >> 4, col8 = (i & 15) * 8;
        *(bf16x8*)&w1t[row][col8] = *(const bf16x8*)&w1tg[row * DIM + col8];
    }
    __syncthreads();

    const int rbase = blockIdx.x * 256 + wave * 32;

    bf16x8 a[2][4];
    #pragma unroll
    for (int rt = 0; rt < 2; ++rt) {
        int row = rbase + rt * 16 + lr;
        bool ok = row < n_vars;
        const float* xp = x + (size_t)row * DIM + lg * 8;
        #pragma unroll
        for (int kt = 0; kt < 4; ++kt) {
            bf16x8 av = {0,0,0,0,0,0,0,0};
            if (ok) {
                float4 f0 = *(const float4*)(xp + kt * 32);
                float4 f1 = *(const float4*)(xp + kt * 32 + 4);
                av[0]=bfc(f0.x); av[1]=bfc(f0.y); av[2]=bfc(f0.z); av[3]=bfc(f0.w);
                av[4]=bfc(f1.x); av[5]=bfc(f1.y); av[6]=bfc(f1.z); av[7]=bfc(f1.w);
            }
            a[rt][kt] = av;
        }
    }

    bf16x8 bb[4];
    #pragma unroll
    for (int kt = 0; kt < 4; ++kt)
        bb[kt] = *(const bf16x8*)&w2tg[lr * DIM + kt * 32 + lg * 8];
    float b2v = (lr < 8) ? b2[lr] : 0.f;

    #pragma unroll
    for (int rt = 0; rt < 2; ++rt) {
        #pragma unroll
        for (int n = 0; n < 8; ++n) {
            f32x4 acc = {0.f, 0.f, 0.f, 0.f};
            #pragma unroll
            for (int kt = 0; kt < 4; ++kt) {
                bf16x8 bf = *(const bf16x8*)&w1t[n * 16 + lr][kt * 32 + lg * 8];
                acc = __builtin_amdgcn_mfma_f32_16x16x32_bf16(a[rt][kt], bf, acc, 0, 0, 0);
            }
            float bcol = b1[n * 16 + lr];
            #pragma unroll
            for (int r = 0; r < 4; ++r) {
                float h = fmaxf(acc[r] + bcol, 0.f);
                hlds[wave][lg * 4 + r][n * 16 + lr] = bfc(h);
            }
        }
        f32x4 acc2 = {0.f, 0.f, 0.f, 0.f};
        #pragma unroll
        for (int kt = 0; kt < 4; ++kt) {
            bf16x8 af = *(const bf16x8*)&hlds[wave][lr][kt * 32 + lg * 8];
            acc2 = __builtin_amdgcn_mfma_f32_16x16x32_bf16(af, bb[kt], acc2, 0, 0, 0);
        }
        if (lr < 8) {
            #pragma unroll
            for (int r = 0; r < 4; ++r)
                lout[wave][lg * 4 + r][lr] = acc2[r] + b2v;
        }
        if (lane < 16) {
            int row = rbase + rt * 16 + lane;
            if (row < n_vars) {
                const float* f = lout[wave][lane];
                unsigned lo = 0u, hi = 0u;
                lo = __builtin_amdgcn_cvt_pk_fp8_f32(f[0], f[1], lo, false);
                lo = __builtin_amdgcn_cvt_pk_fp8_f32(f[2], f[3], lo, true);
                hi = __builtin_amdgcn_cvt_pk_fp8_f32(f[4], f[5], hi, false);
                hi = __builtin_amdgcn_cvt_pk_fp8_f32(f[6], f[7], hi, true);
                lfp8[row] = make_uint2(lo, hi);
            }
        }
    }
}

// exclusive scan each row (width NT1MAX=1024) over tiles
__global__ __launch_bounds__(256) void scanrowV_kernel(
    unsigned* __restrict__ hist, unsigned* __restrict__ btotal)
{
    const int t = threadIdx.x;
    const size_t base = (size_t)blockIdx.x * NT1MAX + t * 4;
    uint4 v = *(const uint4*)(hist + base);
    unsigned pre0 = 0, pre1 = v.x, pre2 = v.x + v.y, pre3 = v.x + v.y + v.z;
    unsigned run = pre3 + v.w;
    __shared__ unsigned ts[256];
    ts[t] = run;
    __syncthreads();
    for (int off = 1; off < 256; off <<= 1) {
        unsigned xv = (t >= off) ? ts[t - off] : 0u;
        __syncthreads();
        ts[t] += xv;
        __syncthreads();
    }
    unsigned ex = ts[t] - run;
    uint4 o = {ex + pre0, ex + pre1, ex + pre2, ex + pre3};
    *(uint4*)(hist + base) = o;
    if (t == 255) btotal[blockIdx.x] = ts[255];
}

// staged scatter into v-group order; payload u32 = voff<<22 | neg<<21 | c
// (baseV computed in prologue from btotalV)
__global__ __launch_bounds__(256) void scatterV_kernel(
    const int* __restrict__ ci, const int* __restrict__ vi,
    const float* __restrict__ pol, const unsigned* __restrict__ histV,
    const unsigned* __restrict__ btotalV, unsigned* __restrict__ A, int n_edges)
{
    __shared__ unsigned sa[TV1];            // 32 KB
    __shared__ unsigned short bmap[TV1];    // 16 KB
    __shared__ unsigned h[NKV], lst[NKV], h2[NKV], gst[NKV];  // 8 KB
    __shared__ unsigned baseVl[NKV];        //  2 KB
    __shared__ unsigned ts[256];
    const int t = threadIdx.x, b = blockIdx.x;

    // prologue: baseV = exclusive scan of btotalV[512]
    {
        unsigned v0 = btotalV[2 * t], v1 = btotalV[2 * t + 1];
        unsigned run = v0 + v1;
        ts[t] = run;
        __syncthreads();
        for (int off = 1; off < 256; off <<= 1) {
            unsigned xv = (t >= off) ? ts[t - off] : 0u;
            __syncthreads();
            ts[t] += xv;
            __syncthreads();
        }
        unsigned ex = ts[t] - run;
        baseVl[2 * t] = ex; baseVl[2 * t + 1] = ex + v0;
    }
    for (int i = t; i < NKV; i += 256) h[i] = 0u;
    __syncthreads();
    const int e0 = b * TV1, e1 = min(e0 + TV1, n_edges), n = e1 - e0;
    for (int e = e0 + t; e < e1; e += 256)
        atomicAdd(&h[((unsigned)vi[e]) >> VSH], 1u);
    __syncthreads();
    unsigned a0 = h[2 * t], a1 = h[2 * t + 1];
    unsigned run = a0 + a1;
    ts[t] = run;
    __syncthreads();
    for (int off = 1; off < 256; off <<= 1) {
        unsigned xv = (t >= off) ? ts[t - off] : 0u;
        __syncthreads();
        ts[t] += xv;
        __syncthreads();
    }
    unsigned ex = ts[t] - run;
    lst[2 * t] = ex; lst[2 * t + 1] = ex + a0;
    h2[2 * t] = ex;  h2[2 * t + 1] = ex + a0;
    __syncthreads();
    for (int e = e0 + t; e < e1; e += 256) {
        unsigned c = (unsigned)ci[e];
        unsigned v = (unsigned)vi[e];
        unsigned neg = (pol[e] < 0.f) ? 1u : 0u;
        unsigned k = v >> VSH;
        unsigned p = atomicAdd(&h2[k], 1u);
        sa[p] = c | (neg << 21) | ((v & ((1u << VSH) - 1u)) << 22);
        bmap[p] = (unsigned short)k;
    }
    for (int i = t; i < NKV; i += 256)
        gst[i] = baseVl[i] + histV[(size_t)i * NT1MAX + b];
    __syncthreads();
    for (int s = t; s < n; s += 256) {
        unsigned k = bmap[s];
        A[gst[k] + (s - lst[k])] = sa[s];
    }
}

// ================= level B: attach sign-applied logits + coarse-c partition ==

__global__ __launch_bounds__(256) void histB_kernel(
    const unsigned* __restrict__ A, const unsigned* __restrict__ baseV,
    unsigned* __restrict__ histB)
{
    __shared__ unsigned h[NKC];
    const int t = threadIdx.x;
    const int vg = blockIdx.x / MAXTV, i = blockIdx.x % MAXTV;
    const unsigned slo = baseV[vg], shi = baseV[vg + 1];
    const unsigned t0 = slo + (unsigned)i * TB;
    if (t0 >= shi) return;
    const unsigned t1 = min(t0 + TB, shi);
    if (t < NKC) h[t] = 0u;
    __syncthreads();
    for (unsigned e = t0 + t; e < t1; e += 256)
        atomicAdd(&h[(A[e] & 0x1FFFFFu) >> 15], 1u);
    __syncthreads();
    if (t < NKC) histB[(size_t)t * (NKV * MAXTV) + blockIdx.x] = h[t];
}

// helper: publish baseV (needed by histB/scatterB segment bounds)
__global__ void baseV_pub_kernel(const unsigned* __restrict__ tv,
                                 unsigned* __restrict__ bv)
{
    if (threadIdx.x == 0) {
        unsigned r = 0;
        for (int k = 0; k < NKV; ++k) { bv[k] = r; r += tv[k]; }
        bv[NKV] = r;
    }
}

// exclusive scan each row (width NKV*MAXTV = 2048) over tiles
__global__ __launch_bounds__(256) void scanrowB_kernel(
    unsigned* __restrict__ hist, unsigned* __restrict__ btotal)
{
    const int t = threadIdx.x;
    const size_t base = (size_t)blockIdx.x * (NKV * MAXTV) + t * 8;
    uint4 v0 = *(const uint4*)(hist + base);
    uint4 v1 = *(const uint4*)(hist + base + 4);
    unsigned p0 = 0, p1 = v0.x, p2 = p1 + v0.y, p3 = p2 + v0.z, p4 = p3 + v0.w;
    unsigned p5 = p4 + v1.x, p6 = p5 + v1.y, p7 = p6 + v1.z;
    unsigned run = p7 + v1.w;
    __shared__ unsigned ts[256];
    ts[t] = run;
    __syncthreads();
    for (int off = 1; off < 256; off <<= 1) {
        unsigned xv = (t >= off) ? ts[t - off] : 0u;
        __syncthreads();
        ts[t] += xv;
        __syncthreads();
    }
    unsigned ex = ts[t] - run;
    uint4 o0 = {ex + p0, ex + p1, ex + p2, ex + p3};
    uint4 o1 = {ex + p4, ex + p5, ex + p6, ex + p7};
    *(uint4*)(hist + base) = o0;
    *(uint4*)(hist + base + 4) = o1;
    if (t == 255) btotal[blockIdx.x] = ts[255];
}

// attach: LDS logit slice + SIGN-APPLY + scatter (baseB scanned in prologue)
__global__ __launch_bounds__(256) void scatterB_kernel(
    const unsigned* __restrict__ A, const uint2* __restrict__ lfp8,
    const unsigned* __restrict__ baseV, const unsigned* __restrict__ histB,
    const unsigned* __restrict__ btotalB, unsigned short* __restrict__ B1,
    uint2* __restrict__ B2, int n_vars)
{
    __shared__ uint2 slice[1 << VSH];       //  8 KB
    __shared__ unsigned short st1[TB];      //  8 KB
    __shared__ uint2 st2[TB];               // 32 KB
    __shared__ unsigned char bmap[TB];      //  4 KB
    __shared__ unsigned h[NKC], lst[NKC], h2[NKC], gst[NKC], baseBl[NKC];
    const int t = threadIdx.x;
    const int vg = blockIdx.x / MAXTV, i = blockIdx.x % MAXTV;
    const unsigned slo = baseV[vg], shi = baseV[vg + 1];
    const unsigned t0 = slo + (unsigned)i * TB;
    if (t0 >= shi) return;
    const unsigned t1 = min(t0 + TB, shi);
    const int n = (int)(t1 - t0);
    if (t < NKC) h[t] = btotalB[t];   // temp: raw totals
    __syncthreads();
    if (t == 0) {
        unsigned r = 0;
        for (int k = 0; k < NKC; ++k) { baseBl[k] = r; r += h[k]; }
    }
    __syncthreads();
    for (int s = t; s < (1 << VSH); s += 256) {
        int v = (vg << VSH) + s;
        slice[s] = (v < n_vars) ? lfp8[v] : make_uint2(0u, 0u);
    }
    if (t < NKC) h[t] = 0u;
    __syncthreads();
    for (unsigned e = t0 + t; e < t1; e += 256)
        atomicAdd(&h[(A[e] & 0x1FFFFFu) >> 15], 1u);
    __syncthreads();
    if (t == 0) {
        unsigned r = 0;
        for (int k = 0; k < NKC; ++k) { lst[k] = r; h2[k] = r; r += h[k]; }
    }
    __syncthreads();
    for (unsigned e = t0 + t; e < t1; e += 256) {
        unsigned a = A[e];
        unsigned c = a & 0x1FFFFFu;
        unsigned k = c >> 15;
        unsigned p = atomicAdd(&h2[k], 1u);
        uint2 g = slice[a >> 22];
        unsigned sm = ((a >> 21) & 1u) * 0x80808080u;  // negation = sign-bit flip
        g.x ^= sm; g.y ^= sm;
        st1[p] = (unsigned short)(c & 0x7FFFu);
        st2[p] = g;
        bmap[p] = (unsigned char)k;
    }
    if (t < NKC) gst[t] = baseBl[t] + histB[(size_t)t * (NKV * MAXTV) + blockIdx.x];
    __syncthreads();
    for (int s = t; s < n; s += 256) {
        unsigned k = bmap[s];
        unsigned pos = gst[k] + (s - lst[k]);
        B1[pos] = st1[s];
        B2[pos] = st2[s];
    }
}

// publish baseB for level-C segment bounds
__global__ void baseB_pub_kernel(const unsigned* __restrict__ tb,
                                 unsigned* __restrict__ bb)
{
    if (threadIdx.x == 0) {
        unsigned r = 0;
        for (int k = 0; k < NKC; ++k) { bb[k] = r; r += tb[k]; }
        bb[NKC] = r;
    }
}

// ================= level C: fine clause-bucket scatter =======================

__global__ __launch_bounds__(256) void histC_kernel(
    const unsigned short* __restrict__ B1, const unsigned* __restrict__ baseB,
    unsigned* __restrict__ histC)
{
    __shared__ unsigned h[64];
    const int t = threadIdx.x;
    const int k1 = blockIdx.x / MAXTC, i = blockIdx.x % MAXTC;
    const unsigned slo = baseB[k1], shi = baseB[k1 + 1];
    const unsigned t0 = slo + (unsigned)i * TC;
    if (t0 >= shi) return;
    const unsigned t1 = min(t0 + TC, shi);
    if (t < 64) h[t] = 0u;
    __syncthreads();
    for (unsigned e = t0 + t; e < t1; e += 256)
        atomicAdd(&h[((unsigned)B1[e] >> 9) & 63u], 1u);
    __syncthreads();
    if (t < 64) histC[(size_t)(k1 * 64 + t) * MAXTC + i] = h[t];
}

__global__ __launch_bounds__(256) void scanrowC_kernel(
    unsigned* __restrict__ histC, unsigned* __restrict__ ctotal)
{
    const int rid = blockIdx.x * 256 + threadIdx.x;
    unsigned r = 0;
    for (int i = 0; i < MAXTC; ++i) {
        unsigned v = histC[(size_t)rid * MAXTC + i];
        histC[(size_t)rid * MAXTC + i] = r;
        r += v;
    }
    ctotal[rid] = r;
}

__global__ __launch_bounds__(256) void bbase_kernel(
    const unsigned* __restrict__ ctotal, unsigned* __restrict__ bbase, int nb)
{
    const int t = threadIdx.x;
    unsigned loc[16];
    unsigned run = 0;
    #pragma unroll
    for (int it = 0; it < 16; ++it) {
        int idx = t * 16 + it;
        unsigned v = (idx < 4096) ? ctotal[idx] : 0u;
        loc[it] = run;
        run += v;
    }
    __shared__ unsigned ts[256];
    ts[t] = run;
    __syncthreads();
    for (int off = 1; off < 256; off <<= 1) {
        unsigned xv = (t >= off) ? ts[t - off] : 0u;
        __syncthreads();
        ts[t] += xv;
        __syncthreads();
    }
    unsigned ex = ts[t] - run;
    #pragma unroll
    for (int it = 0; it < 16; ++it) {
        int idx = t * 16 + it;
        if (idx <= nb) bbase[idx] = ex + loc[it];
    }
}

__global__ __launch_bounds__(256) void scatterC_kernel(
    const unsigned short* __restrict__ B1, const uint2* __restrict__ B2,
    const unsigned* __restrict__ baseB, const unsigned* __restrict__ histC,
    const unsigned* __restrict__ bbase, unsigned short* __restrict__ sortedS,
    uint2* __restrict__ sortedL)
{
    __shared__ unsigned short st1[TC];      //  8 KB
    __shared__ uint2 st2[TC];               // 32 KB
    __shared__ unsigned char bmap[TC];      //  4 KB
    __shared__ unsigned h[64], lst[64], h2[64], gst[64];
    const int t = threadIdx.x;
    const int k1 = blockIdx.x / MAXTC, i = blockIdx.x % MAXTC;
    const unsigned slo = baseB[k1], shi = baseB[k1 + 1];
    const unsigned t0 = slo + (unsigned)i * TC;
    if (t0 >= shi) return;
    const unsigned t1 = min(t0 + TC, shi);
    const int n = (int)(t1 - t0);
    if (t < 64) h[t] = 0u;
    __syncthreads();
    for (unsigned e = t0 + t; e < t1; e += 256)
        atomicAdd(&h[((unsigned)B1[e] >> 9) & 63u], 1u);
    __syncthreads();
    if (t == 0) {
        unsigned r = 0;
        for (int k = 0; k < 64; ++k) { lst[k] = r; h2[k] = r; r += h[k]; }
    }
    __syncthreads();
    for (unsigned e = t0 + t; e < t1; e += 256) {
        unsigned b = (unsigned)B1[e];
        unsigned k2 = (b >> 9) & 63u;
        unsigned p = atomicAdd(&h2[k2], 1u);
        st1[p] = (unsigned short)(b & 0x1FFu);
        st2[p] = B2[e];
        bmap[p] = (unsigned char)k2;
    }
    if (t < 64) {
        unsigned cbk = (unsigned)(k1 * 64 + t);
        gst[t] = bbase[cbk] + histC[(size_t)cbk * MAXTC + i];
    }
    __syncthreads();
    for (int s = t; s < n; s += 256) {
        unsigned k = bmap[s];
        unsigned pos = gst[k] + (s - lst[k]);
        sortedS[pos] = st1[s];
        sortedL[pos] = st2[s];
    }
}

// --- bucket: SINGLE-READ counting-sort + owner-reduce with fused graph fold --
__global__ __launch_bounds__(256) void bucket_kernel(
    const unsigned short* __restrict__ sortedS, const uint2* __restrict__ sortedL,
    const unsigned* __restrict__ bbase, const int* __restrict__ clause_batch,
    float* __restrict__ per_graph, unsigned* __restrict__ gmask,
    int n_clauses, int n_graphs)
{
    __shared__ uint2 sarrL[SARR_CAP];   // 20 KB (aliased as acc in fallback)
    __shared__ unsigned cnt[CB];        //  2 KB (count -> cursor)
    __shared__ unsigned cst[CB + 1];    //  2 KB
    __shared__ float sp[256];           //  1 KB
    __shared__ float pg[MAXSLOT * K];   //  1 KB
    __shared__ unsigned pmask[MAXSLOT];
    __shared__ unsigned wtot[4];
    __shared__ int sh_ghi;

    const int t = threadIdx.x;
    const int lane = t & 63, wv = t >> 6;
    const int bkt = blockIdx.x;
    const int c_base = bkt << CSHIFT;
    const int n_cl = min(CB, n_clauses - c_base);
    const int g_lo = clause_batch[c_base];

    {
        float v = __builtin_amdgcn_cvt_f32_fp8((unsigned)t, 0);
        sp[t] = fmaxf(v, 0.f) + __logf(1.f + __expf(-fabsf(v)));
    }
    for (int i = t; i < CB; i += 256) cnt[i] = 0u;
    for (int i = t; i < MAXSLOT * K; i += 256) pg[i] = 0.f;
    if (t < MAXSLOT) pmask[t] = 0xFFu;
    if (t == 0) sh_ghi = clause_batch[c_base + n_cl - 1];
    __syncthreads();

    const unsigned lo = bbase[bkt], hi = bbase[bkt + 1];
    const int ne = (int)(hi - lo);

    float loss0[K], loss1[K];
    unsigned msk0 = 0u, msk1 = 0u;
    bool have0 = false, have1 = false;

    if (ne <= SARR_CAP) {
        // ---- single read: stage edges in registers + count ----
        unsigned short myS[MAXE];
        uint2 myL[MAXE];
        #pragma unroll
        for (int u = 0; u < MAXE; ++u) {
            unsigned e = lo + t + 256u * u;
            bool ok = e < hi;
            myS[u] = ok ? sortedS[e] : (unsigned short)0xFFFFu;
            myL[u] = ok ? sortedL[e] : make_uint2(0u, 0u);
            if (ok) atomicAdd(&cnt[myS[u] & 511u], 1u);
        }
        __syncthreads();
        unsigned a0 = cnt[2 * t], a1 = cnt[2 * t + 1];
        unsigned run = a0 + a1;
        unsigned incl = run;
        #pragma unroll
        for (int off = 1; off < 64; off <<= 1) {
            unsigned v = __shfl_up(incl, off, 64);
            if (lane >= off) incl += v;
        }
        if (lane == 63) wtot[wv] = incl;
        __syncthreads();
        unsigned wpre = 0;
        #pragma unroll
        for (int w = 0; w < 3; ++w) if (w < wv) wpre += wtot[w];
        unsigned ex = wpre + incl - run;
        cst[2 * t] = ex; cst[2 * t + 1] = ex + a0;
        cnt[2 * t] = ex; cnt[2 * t + 1] = ex + a0;
        if (t == 255) cst[CB] = ex + run;
        __syncthreads();
        // ---- rank-scatter from registers ----
        #pragma unroll
        for (int u = 0; u < MAXE; ++u) {
            if (myS[u] != (unsigned short)0xFFFFu) {
                unsigned p = atomicAdd(&cnt[myS[u] & 511u], 1u);
                sarrL[p] = myL[u];
            }
        }
        __syncthreads();
        #pragma unroll
        for (int oc = 0; oc < 2; ++oc) {
            int cl = 2 * t + oc;
            if (cl >= n_cl) continue;
            unsigned s0 = cst[cl];
            int n = (int)(cst[cl + 1] - s0);
            float sums[K] = {0.f, 0.f, 0.f, 0.f, 0.f, 0.f, 0.f, 0.f};
            unsigned ormask = 0u;
            for (int base = 0; base < n; base += 8) {
                int m = min(8, n - base);
                uint2 gs[8];
                for (int i2 = 0; i2 < m; ++i2) gs[i2] = sarrL[s0 + base + i2];
                for (int i2 = 0; i2 < m; ++i2) {
                    #pragma unroll
                    for (int j = 0; j < 4; ++j) {
                        unsigned b0 = (gs[i2].x >> (8 * j)) & 0xFFu;
                        unsigned b1 = (gs[i2].y >> (8 * j)) & 0xFFu;
                        sums[j]     += sp[b0];
                        sums[j + 4] += sp[b1];
                        ormask |= (b0 - 1u < 0x7Fu) ? (1u << j) : 0u;
                        ormask |= (b1 - 1u < 0x7Fu) ? (1u << (j + 4)) : 0u;
                    }
                }
            }
            float* lss = oc ? loss1 : loss0;
            #pragma unroll
            for (int j = 0; j < K; ++j) {
                float cv = __expf(-sums[j]);
                lss[j] = cv * (-__logf(1.f - cv + EPS));
            }
            if (oc) { msk1 = ormask; have1 = true; }
            else    { msk0 = ormask; have0 = true; }
        }
    } else {
        float* acc = (float*)sarrL;
        unsigned* fmsk = cnt;
        for (int i = t; i < CB * K; i += 256) acc[i] = 0.f;
        for (int i = t; i < CB; i += 256) fmsk[i] = 0u;
        __syncthreads();
        for (unsigned e = lo + t; e < hi; e += 256) {
            unsigned cl = sortedS[e] & 511u;
            uint2 g = sortedL[e];
            unsigned gt0 = 0u;
            #pragma unroll
            for (int j = 0; j < 4; ++j) {
                unsigned b0 = (g.x >> (8 * j)) & 0xFFu;
                unsigned b1 = (g.y >> (8 * j)) & 0xFFu;
                atomicAdd(&acc[cl * K + j], sp[b0]);
                atomicAdd(&acc[cl * K + j + 4], sp[b1]);
                gt0 |= (b0 - 1u < 0x7Fu) ? (1u << j) : 0u;
                gt0 |= (b1 - 1u < 0x7Fu) ? (1u << (j + 4)) : 0u;
            }
            atomicOr(&fmsk[cl], gt0);
        }
        __syncthreads();
        #pragma unroll
        for (int oc = 0; oc < 2; ++oc) {
            int cl = 2 * t + oc;
            if (cl >= n_cl) continue;
            float* lss = oc ? loss1 : loss0;
            #pragma unroll
            for (int j = 0; j < K; ++j) {
                float cv = __expf(-acc[cl * K + j]);
                lss[j] = cv * (-__logf(1.f - cv + EPS));
            }
            if (oc) { msk1 = fmsk[cl]; have1 = true; }
            else    { msk0 = fmsk[cl]; have0 = true; }
        }
    }

    if (have0) {
        int slot0 = clause_batch[c_base + 2 * t] - g_lo;
        int slot1 = have1 ? (clause_batch[c_base + 2 * t + 1] - g_lo) : -1;
        if (have1 && slot1 == slot0) {
            #pragma unroll
            for (int j = 0; j < K; ++j) loss0[j] += loss1[j];
            msk0 &= msk1;
            have1 = false;
        }
        if (slot0 < MAXSLOT) {
            #pragma unroll
            for (int j = 0; j < K; ++j) atomicAdd(&pg[slot0 * K + j], loss0[j]);
            atomicAnd(&pmask[slot0], msk0);
        } else {
            #pragma unroll
            for (int j = 0; j < K; ++j) atomicAdd(&per_graph[(size_t)(g_lo + slot0) * K + j], loss0[j]);
            atomicAnd(&gmask[g_lo + slot0], msk0);
        }
        if (have1) {
            if (slot1 < MAXSLOT) {
                #pragma unroll
                for (int j = 0; j < K; ++j) atomicAdd(&pg[slot1 * K + j], loss1[j]);
                atomicAnd(&pmask[slot1], msk1);
            } else {
                #pragma unroll
                for (int j = 0; j < K; ++j) atomicAdd(&per_graph[(size_t)(g_lo + slot1) * K + j], loss1[j]);
                atomicAnd(&gmask[g_lo + slot1], msk1);
            }
        }
    }
    __syncthreads();

    const int nslots = min(sh_ghi - g_lo + 1, MAXSLOT);
    if (t < nslots * K) {
        int s = t >> 3, j = t & 7;
        atomicAdd(&per_graph[(size_t)(g_lo + s) * K + j], pg[s * K + j]);
    }
    if (t < nslots) atomicAnd(&gmask[g_lo + t], pmask[t]);
}

// ---------------- Final: per-graph sqrt, sort-8, cost dot, solved ------------
__global__ __launch_bounds__(256) void final_kernel(
    const float* __restrict__ per_graph, const unsigned* __restrict__ gmask,
    int n_graphs, float* __restrict__ out)
{
    const int t = threadIdx.x;
    float dot = 0.f;
    if (t < n_graphs) {
        float v[K];
        #pragma unroll
        for (int j = 0; j < K; ++j)
            v[j] = sqrtf(per_graph[(size_t)t * K + j] + SQRT_EPS) - sqrtf(SQRT_EPS);
        #pragma unroll
        for (int i = 1; i < K; ++i) {
            float key = v[i];
            int j = i - 1;
            while (j >= 0 && v[j] < key) { v[j + 1] = v[j]; --j; }
            v[j + 1] = key;
        }
        #pragma unroll
        for (int i = 0; i < K; ++i)
            dot = fmaf(v[i], (float)((i + 1) * (i + 1)), dot);
        out[1 + t] = (gmask[t] & 0xFFu) ? 1.f : 0.f;
    }
    __shared__ float red[256];
    red[t] = dot;
    __syncthreads();
    for (int s = 128; s >= 1; s >>= 1) {
        if (t < s) red[t] += red[t + s];
        __syncthreads();
    }
    if (t == 0) out[0] = red[0] * (1.f / 204.f);
}

// ---------------------------------------------------------------------------
extern "C" void kernel_launch(void* const* d_in, const int* in_sizes, int n_in,
                              void* d_out, int out_size, void* d_ws, size_t ws_size,
                              hipStream_t stream) {
    const float* x   = (const float*)d_in[0];
    const float* pol = (const float*)d_in[1];
    const int* vi    = (const int*)d_in[2];
    const int* ci    = (const int*)d_in[3];
    const int* cb    = (const int*)d_in[4];
    const float* W1  = (const float*)d_in[5];
    const float* b1  = (const float*)d_in[6];
    const float* W2  = (const float*)d_in[7];
    const float* b2  = (const float*)d_in[8];

    const int n_vars    = in_sizes[0] / DIM;
    const int n_edges   = in_sizes[1];
    const int n_clauses = in_sizes[4];
    const int n_graphs  = out_size - 1;
    const int nb        = (n_clauses + CB - 1) / CB;
    const int nt1       = (n_edges + TV1 - 1) / TV1;
    const int mlpB      = (n_vars + 255) / 256;

    // ---- workspace layout ----
    char* ws = (char*)d_ws;
    size_t off = 0;
    auto alloc = [&](size_t bytes) { char* p = ws + off; off += (bytes + 255) & ~(size_t)255; return p; };
    uint2*    lfp8   = (uint2*)alloc((size_t)n_vars * 8);
    unsigned* A      = (unsigned*)alloc((size_t)n_edges * 4);
    unsigned short* B1 = (unsigned short*)alloc((size_t)n_edges * 2);
    uint2*    B2     = (uint2*)alloc((size_t)n_edges * 8);
    uint2*    sortedL= (uint2*)alloc((size_t)n_edges * 8);
    unsigned* histV  = (unsigned*)alloc((size_t)NKV * NT1MAX * 4);
    unsigned* histB  = (unsigned*)alloc((size_t)NKC * NKV * MAXTV * 4);
    unsigned* histC  = (unsigned*)alloc((size_t)4096 * MAXTC * 4);
    unsigned* btotalV= (unsigned*)alloc((size_t)(NKV + 1) * 4);
    unsigned* baseV  = (unsigned*)alloc((size_t)(NKV + 1) * 4);
    unsigned* btotalB= (unsigned*)alloc((size_t)(NKC + 1) * 4);
    unsigned* baseB  = (unsigned*)alloc((size_t)(NKC + 1) * 4);
    unsigned* ctotal = (unsigned*)alloc((size_t)4096 * 4);
    unsigned* bbase  = (unsigned*)alloc((size_t)(NBMAX + 1) * 4);
    float*    per_graph = (float*)alloc((size_t)n_graphs * K * 4);
    unsigned* gmask  = (unsigned*)alloc((size_t)n_graphs * 4);
    unsigned short* w1tg = (unsigned short*)alloc((size_t)DIM * DIM * 2);
    unsigned short* w2tg = (unsigned short*)alloc((size_t)16 * DIM * 2);
    unsigned short* sortedS = (unsigned short*)A;   // alias: A dead after scatterB

    hipMemsetAsync(histV, 0, (size_t)NKV * NT1MAX * 4, stream);
    hipMemsetAsync(histB, 0, (size_t)NKC * NKV * MAXTV * 4, stream);
    hipMemsetAsync(histC, 0, (size_t)4096 * MAXTC * 4, stream);
    hipMemsetAsync(per_graph, 0, (size_t)n_graphs * K * 4, stream);
    hipMemsetAsync(gmask, 0xFF, (size_t)n_graphs * 4, stream);

    prep_kernel<<<1, 512, 0, stream>>>(W1, W2, w1tg, w2tg);
    mlp_histV_kernel<<<mlpB + nt1, 512, 0, stream>>>(x, w1tg, b1, w2tg, b2,
                                                     lfp8, n_vars, vi, histV,
                                                     n_edges, mlpB);

    scanrowV_kernel<<<NKV, 256, 0, stream>>>(histV, btotalV);
    baseV_pub_kernel<<<1, 64, 0, stream>>>(btotalV, baseV);   // for histB/scatterB bounds
    scatterV_kernel<<<nt1, 256, 0, stream>>>(ci, vi, pol, histV, btotalV, A, n_edges);

    histB_kernel<<<NKV * MAXTV, 256, 0, stream>>>(A, baseV, histB);
    scanrowB_kernel<<<NKC, 256, 0, stream>>>(histB, btotalB);
    baseB_pub_kernel<<<1, 64, 0, stream>>>(btotalB, baseB);   // for level-C bounds
    scatterB_kernel<<<NKV * MAXTV, 256, 0, stream>>>(A, lfp8, baseV, histB, btotalB,
                                                     B1, B2, n_vars);

    histC_kernel<<<NKC * MAXTC, 256, 0, stream>>>(B1, baseB, histC);
    scanrowC_kernel<<<16, 256, 0, stream>>>(histC, ctotal);
    bbase_kernel<<<1, 256, 0, stream>>>(ctotal, bbase, nb);
    scatterC_kernel<<<NKC * MAXTC, 256, 0, stream>>>(B1, B2, baseB, histC, bbase,
                                                     sortedS, sortedL);

    bucket_kernel<<<nb, 256, 0, stream>>>(sortedS, sortedL, bbase, cb,
                                          per_graph, gmask, n_clauses, n_graphs);
    final_kernel<<<1, 256, 0, stream>>>(per_graph, gmask, n_graphs, (float*)d_out);
}

// Round 17
// 415.679 us; speedup vs baseline: 1.1724x; 1.0899x over previous
//
#include <hip/hip_runtime.h>
#include <hip/hip_bf16.h>

#define DIM 128
#define K 8
#define EPS 1e-8f
#define SQRT_EPS 1e-6f

#define CB 512           // clauses per fine bucket
#define CSHIFT 9
#define MAXSLOT 32       // graph slots per bucket
#define SARR_CAP 2560    // mean 1536, +26 sigma
#define MAXE 10          // SARR_CAP/256 register-staged edges per thread

// input tiles
#define TV1 8192
#define NT1MAX 1024
// v-level: 512 groups of 1024 vars
#define NKV 512
#define VSH 10
// attach/coarse-c level
#define TB 4096
#define MAXTV 4
#define NKC 64           // coarse clause groups (c>>15)
// fine-c level (virtual: counts only, no materialized sort)
#define TC 4096
#define MAXTC 32

typedef __attribute__((ext_vector_type(8))) short bf16x8;
typedef __attribute__((ext_vector_type(4))) float f32x4;

__device__ inline short bfc(float f) {
    union { __hip_bfloat16 h; short s; } u;
    u.h = __float2bfloat16(f);
    return u.s;
}

#define LDW 136
#define NW 8   // waves per mlp block

// ---------------- one-shot: transpose W1,W2 to bf16 in global ----------------
__global__ __launch_bounds__(512) void prep_kernel(
    const float* __restrict__ W1, const float* __restrict__ W2,
    unsigned short* __restrict__ w1tg, unsigned short* __restrict__ w2tg)
{
    const int t = threadIdx.x;
    for (int i = t; i < DIM * DIM; i += 512) {
        int r = i >> 7, c = i & 127;
        w1tg[c * DIM + r] = (unsigned short)bfc(W1[i]);
    }
    for (int i = t; i < 16 * DIM; i += 512) {
        int c = i >> 7, j = i & 127;
        w2tg[c * DIM + j] = (c < 8) ? (unsigned short)bfc(W2[j * 8 + c])
                                    : (unsigned short)0;
    }
}

// -------- fused: MLP (blocks < mlpB) || histV (blocks >= mlpB) ---------------
__global__ __launch_bounds__(512) void mlp_histV_kernel(
    const float* __restrict__ x, const unsigned short* __restrict__ w1tg,
    const float* __restrict__ b1, const unsigned short* __restrict__ w2tg,
    const float* __restrict__ b2, uint2* __restrict__ lfp8, int n_vars,
    const int* __restrict__ vi, unsigned* __restrict__ histV, int n_edges,
    int mlpB)
{
    __shared__ __align__(16) short w1t[DIM][LDW];       // 34816 B
    __shared__ __align__(16) short hlds[NW][16][LDW];   // 34816 B
    __shared__ __align__(16) float lout[NW][16][8];     //  4096 B
    __shared__ unsigned hl[NKV];                        //  2048 B

    const int t = threadIdx.x;

    if ((int)blockIdx.x >= mlpB) {
        const int b = (int)blockIdx.x - mlpB;
        for (int i = t; i < NKV; i += 512) hl[i] = 0u;
        __syncthreads();
        const int e0 = b * TV1, e1 = min(e0 + TV1, n_edges);
        for (int e = e0 + t; e < e1; e += 512)
            atomicAdd(&hl[((unsigned)vi[e]) >> VSH], 1u);
        __syncthreads();
        for (int i = t; i < NKV; i += 512) histV[(size_t)i * NT1MAX + b] = hl[i];
        return;
    }

    const int wave = t >> 6, lane = t & 63;
    const int lr = lane & 15, lg = lane >> 4;

    for (int i = t; i < DIM * DIM / 8; i += 512) {
        int row = i >> 4, col8 = (i & 15) * 8;
        *(bf16x8*)&w1t[row][col8] = *(const bf16x8*)&w1tg[row * DIM + col8];
    }
    __syncthreads();

    const int rbase = blockIdx.x * 256 + wave * 32;

    bf16x8 a[2][4];
    #pragma unroll
    for (int rt = 0; rt < 2; ++rt) {
        int row = rbase + rt * 16 + lr;
        bool ok = row < n_vars;
        const float* xp = x + (size_t)row * DIM + lg * 8;
        #pragma unroll
        for (int kt = 0; kt < 4; ++kt) {
            bf16x8 av = {0,0,0,0,0,0,0,0};
            if (ok) {
                float4 f0 = *(const float4*)(xp + kt * 32);
                float4 f1 = *(const float4*)(xp + kt * 32 + 4);
                av[0]=bfc(f0.x); av[1]=bfc(f0.y); av[2]=bfc(f0.z); av[3]=bfc(f0.w);
                av[4]=bfc(f1.x); av[5]=bfc(f1.y); av[6]=bfc(f1.z); av[7]=bfc(f1.w);
            }
            a[rt][kt] = av;
        }
    }

    bf16x8 bb[4];
    #pragma unroll
    for (int kt = 0; kt < 4; ++kt)
        bb[kt] = *(const bf16x8*)&w2tg[lr * DIM + kt * 32 + lg * 8];
    float b2v = (lr < 8) ? b2[lr] : 0.f;

    #pragma unroll
    for (int rt = 0; rt < 2; ++rt) {
        #pragma unroll
        for (int n = 0; n < 8; ++n) {
            f32x4 acc = {0.f, 0.f, 0.f, 0.f};
            #pragma unroll
            for (int kt = 0; kt < 4; ++kt) {
                bf16x8 bf = *(const bf16x8*)&w1t[n * 16 + lr][kt * 32 + lg * 8];
                acc = __builtin_amdgcn_mfma_f32_16x16x32_bf16(a[rt][kt], bf, acc, 0, 0, 0);
            }
            float bcol = b1[n * 16 + lr];
            #pragma unroll
            for (int r = 0; r < 4; ++r) {
                float h = fmaxf(acc[r] + bcol, 0.f);
                hlds[wave][lg * 4 + r][n * 16 + lr] = bfc(h);
            }
        }
        f32x4 acc2 = {0.f, 0.f, 0.f, 0.f};
        #pragma unroll
        for (int kt = 0; kt < 4; ++kt) {
            bf16x8 af = *(const bf16x8*)&hlds[wave][lr][kt * 32 + lg * 8];
            acc2 = __builtin_amdgcn_mfma_f32_16x16x32_bf16(af, bb[kt], acc2, 0, 0, 0);
        }
        if (lr < 8) {
            #pragma unroll
            for (int r = 0; r < 4; ++r)
                lout[wave][lg * 4 + r][lr] = acc2[r] + b2v;
        }
        if (lane < 16) {
            int row = rbase + rt * 16 + lane;
            if (row < n_vars) {
                const float* f = lout[wave][lane];
                unsigned lo = 0u, hi = 0u;
                lo = __builtin_amdgcn_cvt_pk_fp8_f32(f[0], f[1], lo, false);
                lo = __builtin_amdgcn_cvt_pk_fp8_f32(f[2], f[3], lo, true);
                hi = __builtin_amdgcn_cvt_pk_fp8_f32(f[4], f[5], hi, false);
                hi = __builtin_amdgcn_cvt_pk_fp8_f32(f[6], f[7], hi, true);
                lfp8[row] = make_uint2(lo, hi);
            }
        }
    }
}

// exclusive scan each row (width NT1MAX=1024) over tiles
__global__ __launch_bounds__(256) void scanrowV_kernel(
    unsigned* __restrict__ hist, unsigned* __restrict__ btotal)
{
    const int t = threadIdx.x;
    const size_t base = (size_t)blockIdx.x * NT1MAX + t * 4;
    uint4 v = *(const uint4*)(hist + base);
    unsigned pre0 = 0, pre1 = v.x, pre2 = v.x + v.y, pre3 = v.x + v.y + v.z;
    unsigned run = pre3 + v.w;
    __shared__ unsigned ts[256];
    ts[t] = run;
    __syncthreads();
    for (int off = 1; off < 256; off <<= 1) {
        unsigned xv = (t >= off) ? ts[t - off] : 0u;
        __syncthreads();
        ts[t] += xv;
        __syncthreads();
    }
    unsigned ex = ts[t] - run;
    uint4 o = {ex + pre0, ex + pre1, ex + pre2, ex + pre3};
    *(uint4*)(hist + base) = o;
    if (t == 255) btotal[blockIdx.x] = ts[255];
}

// staged scatter into v-group order; payload u32 = voff<<22 | neg<<21 | c
__global__ __launch_bounds__(256) void scatterV_kernel(
    const int* __restrict__ ci, const int* __restrict__ vi,
    const float* __restrict__ pol, const unsigned* __restrict__ histV,
    const unsigned* __restrict__ btotalV, unsigned* __restrict__ A, int n_edges)
{
    __shared__ unsigned sa[TV1];            // 32 KB
    __shared__ unsigned short bmap[TV1];    // 16 KB
    __shared__ unsigned h[NKV], lst[NKV], h2[NKV], gst[NKV];  // 8 KB
    __shared__ unsigned baseVl[NKV];        //  2 KB
    __shared__ unsigned ts[256];
    const int t = threadIdx.x, b = blockIdx.x;

    {
        unsigned v0 = btotalV[2 * t], v1 = btotalV[2 * t + 1];
        unsigned run = v0 + v1;
        ts[t] = run;
        __syncthreads();
        for (int off = 1; off < 256; off <<= 1) {
            unsigned xv = (t >= off) ? ts[t - off] : 0u;
            __syncthreads();
            ts[t] += xv;
            __syncthreads();
        }
        unsigned ex = ts[t] - run;
        baseVl[2 * t] = ex; baseVl[2 * t + 1] = ex + v0;
    }
    for (int i = t; i < NKV; i += 256) h[i] = 0u;
    __syncthreads();
    const int e0 = b * TV1, e1 = min(e0 + TV1, n_edges), n = e1 - e0;
    for (int e = e0 + t; e < e1; e += 256)
        atomicAdd(&h[((unsigned)vi[e]) >> VSH], 1u);
    __syncthreads();
    unsigned a0 = h[2 * t], a1 = h[2 * t + 1];
    unsigned run = a0 + a1;
    ts[t] = run;
    __syncthreads();
    for (int off = 1; off < 256; off <<= 1) {
        unsigned xv = (t >= off) ? ts[t - off] : 0u;
        __syncthreads();
        ts[t] += xv;
        __syncthreads();
    }
    unsigned ex = ts[t] - run;
    lst[2 * t] = ex; lst[2 * t + 1] = ex + a0;
    h2[2 * t] = ex;  h2[2 * t + 1] = ex + a0;
    __syncthreads();
    for (int e = e0 + t; e < e1; e += 256) {
        unsigned c = (unsigned)ci[e];
        unsigned v = (unsigned)vi[e];
        unsigned neg = (pol[e] < 0.f) ? 1u : 0u;
        unsigned k = v >> VSH;
        unsigned p = atomicAdd(&h2[k], 1u);
        sa[p] = c | (neg << 21) | ((v & ((1u << VSH) - 1u)) << 22);
        bmap[p] = (unsigned short)k;
    }
    for (int i = t; i < NKV; i += 256)
        gst[i] = baseVl[i] + histV[(size_t)i * NT1MAX + b];
    __syncthreads();
    for (int s = t; s < n; s += 256) {
        unsigned k = bmap[s];
        A[gst[k] + (s - lst[k])] = sa[s];
    }
}

// ================= level B: attach sign-applied logits + coarse-c partition ==

__global__ __launch_bounds__(256) void histB_kernel(
    const unsigned* __restrict__ A, const unsigned* __restrict__ baseV,
    unsigned* __restrict__ histB)
{
    __shared__ unsigned h[NKC];
    const int t = threadIdx.x;
    const int vg = blockIdx.x / MAXTV, i = blockIdx.x % MAXTV;
    const unsigned slo = baseV[vg], shi = baseV[vg + 1];
    const unsigned t0 = slo + (unsigned)i * TB;
    if (t0 >= shi) return;
    const unsigned t1 = min(t0 + TB, shi);
    if (t < NKC) h[t] = 0u;
    __syncthreads();
    for (unsigned e = t0 + t; e < t1; e += 256)
        atomicAdd(&h[(A[e] & 0x1FFFFFu) >> 15], 1u);
    __syncthreads();
    if (t < NKC) histB[(size_t)t * (NKV * MAXTV) + blockIdx.x] = h[t];
}

__global__ void baseV_pub_kernel(const unsigned* __restrict__ tv,
                                 unsigned* __restrict__ bv)
{
    if (threadIdx.x == 0) {
        unsigned r = 0;
        for (int k = 0; k < NKV; ++k) { bv[k] = r; r += tv[k]; }
        bv[NKV] = r;
    }
}

// exclusive scan each row (width NKV*MAXTV = 2048) over tiles
__global__ __launch_bounds__(256) void scanrowB_kernel(
    unsigned* __restrict__ hist, unsigned* __restrict__ btotal)
{
    const int t = threadIdx.x;
    const size_t base = (size_t)blockIdx.x * (NKV * MAXTV) + t * 8;
    uint4 v0 = *(const uint4*)(hist + base);
    uint4 v1 = *(const uint4*)(hist + base + 4);
    unsigned p0 = 0, p1 = v0.x, p2 = p1 + v0.y, p3 = p2 + v0.z, p4 = p3 + v0.w;
    unsigned p5 = p4 + v1.x, p6 = p5 + v1.y, p7 = p6 + v1.z;
    unsigned run = p7 + v1.w;
    __shared__ unsigned ts[256];
    ts[t] = run;
    __syncthreads();
    for (int off = 1; off < 256; off <<= 1) {
        unsigned xv = (t >= off) ? ts[t - off] : 0u;
        __syncthreads();
        ts[t] += xv;
        __syncthreads();
    }
    unsigned ex = ts[t] - run;
    uint4 o0 = {ex + p0, ex + p1, ex + p2, ex + p3};
    uint4 o1 = {ex + p4, ex + p5, ex + p6, ex + p7};
    *(uint4*)(hist + base) = o0;
    *(uint4*)(hist + base + 4) = o1;
    if (t == 255) btotal[blockIdx.x] = ts[255];
}

__global__ void baseB_pub_kernel(const unsigned* __restrict__ tb,
                                 unsigned* __restrict__ bb)
{
    if (threadIdx.x == 0) {
        unsigned r = 0;
        for (int k = 0; k < NKC; ++k) { bb[k] = r; r += tb[k]; }
        bb[NKC] = r;
    }
}

// attach: LDS logit slice + SIGN-APPLY + scatter (baseB scanned in prologue)
__global__ __launch_bounds__(256) void scatterB_kernel(
    const unsigned* __restrict__ A, const uint2* __restrict__ lfp8,
    const unsigned* __restrict__ baseV, const unsigned* __restrict__ histB,
    const unsigned* __restrict__ btotalB, unsigned short* __restrict__ B1,
    uint2* __restrict__ B2, int n_vars)
{
    __shared__ uint2 slice[1 << VSH];       //  8 KB
    __shared__ unsigned short st1[TB];      //  8 KB
    __shared__ uint2 st2[TB];               // 32 KB
    __shared__ unsigned char bmap[TB];      //  4 KB
    __shared__ unsigned h[NKC], lst[NKC], h2[NKC], gst[NKC], baseBl[NKC];
    const int t = threadIdx.x;
    const int vg = blockIdx.x / MAXTV, i = blockIdx.x % MAXTV;
    const unsigned slo = baseV[vg], shi = baseV[vg + 1];
    const unsigned t0 = slo + (unsigned)i * TB;
    if (t0 >= shi) return;
    const unsigned t1 = min(t0 + TB, shi);
    const int n = (int)(t1 - t0);
    if (t < NKC) h[t] = btotalB[t];
    __syncthreads();
    if (t == 0) {
        unsigned r = 0;
        for (int k = 0; k < NKC; ++k) { baseBl[k] = r; r += h[k]; }
    }
    __syncthreads();
    for (int s = t; s < (1 << VSH); s += 256) {
        int v = (vg << VSH) + s;
        slice[s] = (v < n_vars) ? lfp8[v] : make_uint2(0u, 0u);
    }
    if (t < NKC) h[t] = 0u;
    __syncthreads();
    for (unsigned e = t0 + t; e < t1; e += 256)
        atomicAdd(&h[(A[e] & 0x1FFFFFu) >> 15], 1u);
    __syncthreads();
    if (t == 0) {
        unsigned r = 0;
        for (int k = 0; k < NKC; ++k) { lst[k] = r; h2[k] = r; r += h[k]; }
    }
    __syncthreads();
    for (unsigned e = t0 + t; e < t1; e += 256) {
        unsigned a = A[e];
        unsigned c = a & 0x1FFFFFu;
        unsigned k = c >> 15;
        unsigned p = atomicAdd(&h2[k], 1u);
        uint2 g = slice[a >> 22];
        unsigned sm = ((a >> 21) & 1u) * 0x80808080u;
        g.x ^= sm; g.y ^= sm;
        st1[p] = (unsigned short)(c & 0x7FFFu);
        st2[p] = g;
        bmap[p] = (unsigned char)k;
    }
    if (t < NKC) gst[t] = baseBl[t] + histB[(size_t)t * (NKV * MAXTV) + blockIdx.x];
    __syncthreads();
    for (int s = t; s < n; s += 256) {
        unsigned k = bmap[s];
        unsigned pos = gst[k] + (s - lst[k]);
        B1[pos] = st1[s];
        B2[pos] = st2[s];
    }
}

// --------- histC: raw per-(segment,tile) fine-bin counts, tile-major ---------
__global__ __launch_bounds__(256) void histC_kernel(
    const unsigned short* __restrict__ B1, const unsigned* __restrict__ baseB,
    unsigned* __restrict__ histC)
{
    __shared__ unsigned h[64];
    const int t = threadIdx.x;
    const int k1 = blockIdx.x / MAXTC, i = blockIdx.x % MAXTC;
    const unsigned slo = baseB[k1], shi = baseB[k1 + 1];
    const unsigned t0 = slo + (unsigned)i * TC;
    if (t0 >= shi) return;
    const unsigned t1 = min(t0 + TC, shi);
    if (t < 64) h[t] = 0u;
    __syncthreads();
    for (unsigned e = t0 + t; e < t1; e += 256)
        atomicAdd(&h[((unsigned)B1[e] >> 9) & 63u], 1u);
    __syncthreads();
    if (t < 64) histC[((size_t)(k1 * MAXTC + i)) * 64 + t] = h[t];
}

// --- bucket: tile-run gather + counting-sort + owner-reduce + fused fold -----
__global__ __launch_bounds__(256) void bucket_kernel(
    const unsigned short* __restrict__ B1, const uint2* __restrict__ B2,
    const unsigned* __restrict__ baseB, const unsigned* __restrict__ histC,
    const int* __restrict__ clause_batch,
    float* __restrict__ per_graph, unsigned* __restrict__ gmask,
    int n_clauses, int n_graphs)
{
    __shared__ uint2 sarrL[SARR_CAP];   // 20 KB (aliased as acc in fallback)
    __shared__ unsigned hrow[MAXTC * 64]; // 8 KB raw counts [tile][bin]
    __shared__ unsigned runstart[MAXTC];
    __shared__ unsigned runpre[MAXTC + 1];
    __shared__ unsigned cnt[CB];        //  2 KB
    __shared__ unsigned cst[CB + 1];    //  2 KB
    __shared__ float sp[256];           //  1 KB
    __shared__ float pg[MAXSLOT * K];   //  1 KB
    __shared__ unsigned pmask[MAXSLOT];
    __shared__ unsigned wtot[4];
    __shared__ int sh_ghi;

    const int t = threadIdx.x;
    const int lane = t & 63, wv = t >> 6;
    const int bkt = blockIdx.x;
    const int k1 = bkt >> 6, f = bkt & 63;
    const int c_base = bkt << CSHIFT;
    const int n_cl = min(CB, n_clauses - c_base);
    const int g_lo = clause_batch[c_base];

    {
        float v = __builtin_amdgcn_cvt_f32_fp8((unsigned)t, 0);
        sp[t] = fmaxf(v, 0.f) + __logf(1.f + __expf(-fabsf(v)));
    }
    for (int i = t; i < CB; i += 256) cnt[i] = 0u;
    for (int i = t; i < MAXSLOT * K; i += 256) pg[i] = 0.f;
    if (t < MAXSLOT) pmask[t] = 0xFFu;
    if (t == 0) sh_ghi = clause_batch[c_base + n_cl - 1];

    // load raw counts for this coarse segment (tile-major rows, coalesced)
    for (int i = t; i < MAXTC * 64; i += 256)
        hrow[i] = histC[((size_t)(k1 * MAXTC)) * 64 + i];
    __syncthreads();

    // per-tile run offset (prefix over bins < f) and length; wave-0 scan
    const unsigned slo = baseB[k1];
    if (t < MAXTC) {
        unsigned off = 0;
        for (int fp = 0; fp < f; ++fp) off += hrow[t * 64 + fp];
        unsigned len = hrow[t * 64 + f];
        runstart[t] = slo + (unsigned)t * TC + off;
        // inclusive scan of len across lanes 0..31 (wave0 subset)
        unsigned incl = len;
        #pragma unroll
        for (int o = 1; o < 32; o <<= 1) {
            unsigned v = __shfl_up(incl, o, 64);
            if (lane >= o) incl += v;
        }
        runpre[t + 1] = incl;
        if (t == 0) runpre[0] = 0;
    }
    __syncthreads();
    const int ne = (int)runpre[MAXTC];

    float loss0[K], loss1[K];
    unsigned msk0 = 0u, msk1 = 0u;
    bool have0 = false, have1 = false;

    if (ne <= SARR_CAP) {
        // ---- register staging with run-table address translation ----
        unsigned short myS[MAXE];
        uint2 myL[MAXE];
        #pragma unroll
        for (int u = 0; u < MAXE; ++u) {
            int e = t + 256 * u;
            if (e < ne) {
                int lo2 = 0, hi2 = MAXTC;
                while (lo2 + 1 < hi2) {
                    int mid = (lo2 + hi2) >> 1;
                    if (runpre[mid] <= (unsigned)e) lo2 = mid; else hi2 = mid;
                }
                unsigned pos = runstart[lo2] + ((unsigned)e - runpre[lo2]);
                myS[u] = (unsigned short)(B1[pos] & 511u);
                myL[u] = B2[pos];
                atomicAdd(&cnt[myS[u]], 1u);
            } else {
                myS[u] = (unsigned short)0xFFFFu;
                myL[u] = make_uint2(0u, 0u);
            }
        }
        __syncthreads();
        unsigned a0 = cnt[2 * t], a1 = cnt[2 * t + 1];
        unsigned run = a0 + a1;
        unsigned incl = run;
        #pragma unroll
        for (int off = 1; off < 64; off <<= 1) {
            unsigned v = __shfl_up(incl, off, 64);
            if (lane >= off) incl += v;
        }
        if (lane == 63) wtot[wv] = incl;
        __syncthreads();
        unsigned wpre = 0;
        #pragma unroll
        for (int w = 0; w < 3; ++w) if (w < wv) wpre += wtot[w];
        unsigned ex = wpre + incl - run;
        cst[2 * t] = ex; cst[2 * t + 1] = ex + a0;
        cnt[2 * t] = ex; cnt[2 * t + 1] = ex + a0;
        if (t == 255) cst[CB] = ex + run;
        __syncthreads();
        #pragma unroll
        for (int u = 0; u < MAXE; ++u) {
            if (myS[u] != (unsigned short)0xFFFFu) {
                unsigned p = atomicAdd(&cnt[myS[u]], 1u);
                sarrL[p] = myL[u];
            }
        }
        __syncthreads();
        #pragma unroll
        for (int oc = 0; oc < 2; ++oc) {
            int cl = 2 * t + oc;
            if (cl >= n_cl) continue;
            unsigned s0 = cst[cl];
            int n = (int)(cst[cl + 1] - s0);
            float sums[K] = {0.f, 0.f, 0.f, 0.f, 0.f, 0.f, 0.f, 0.f};
            unsigned ormask = 0u;
            for (int base = 0; base < n; base += 8) {
                int m = min(8, n - base);
                uint2 gs[8];
                for (int i2 = 0; i2 < m; ++i2) gs[i2] = sarrL[s0 + base + i2];
                for (int i2 = 0; i2 < m; ++i2) {
                    #pragma unroll
                    for (int j = 0; j < 4; ++j) {
                        unsigned b0 = (gs[i2].x >> (8 * j)) & 0xFFu;
                        unsigned b1 = (gs[i2].y >> (8 * j)) & 0xFFu;
                        sums[j]     += sp[b0];
                        sums[j + 4] += sp[b1];
                        ormask |= (b0 - 1u < 0x7Fu) ? (1u << j) : 0u;
                        ormask |= (b1 - 1u < 0x7Fu) ? (1u << (j + 4)) : 0u;
                    }
                }
            }
            float* lss = oc ? loss1 : loss0;
            #pragma unroll
            for (int j = 0; j < K; ++j) {
                float cv = __expf(-sums[j]);
                lss[j] = cv * (-__logf(1.f - cv + EPS));
            }
            if (oc) { msk1 = ormask; have1 = true; }
            else    { msk0 = ormask; have0 = true; }
        }
    } else {
        // ---- fallback: LDS-atomic accumulate with run translation ----
        float* acc = (float*)sarrL;        // 16 KB alias
        unsigned* fmsk = cnt;
        for (int i = t; i < CB * K; i += 256) acc[i] = 0.f;
        for (int i = t; i < CB; i += 256) fmsk[i] = 0u;
        __syncthreads();
        for (int e = t; e < ne; e += 256) {
            int lo2 = 0, hi2 = MAXTC;
            while (lo2 + 1 < hi2) {
                int mid = (lo2 + hi2) >> 1;
                if (runpre[mid] <= (unsigned)e) lo2 = mid; else hi2 = mid;
            }
            unsigned pos = runstart[lo2] + ((unsigned)e - runpre[lo2]);
            unsigned cl = B1[pos] & 511u;
            uint2 g = B2[pos];
            unsigned gt0 = 0u;
            #pragma unroll
            for (int j = 0; j < 4; ++j) {
                unsigned b0 = (g.x >> (8 * j)) & 0xFFu;
                unsigned b1 = (g.y >> (8 * j)) & 0xFFu;
                atomicAdd(&acc[cl * K + j], sp[b0]);
                atomicAdd(&acc[cl * K + j + 4], sp[b1]);
                gt0 |= (b0 - 1u < 0x7Fu) ? (1u << j) : 0u;
                gt0 |= (b1 - 1u < 0x7Fu) ? (1u << (j + 4)) : 0u;
            }
            atomicOr(&fmsk[cl], gt0);
        }
        __syncthreads();
        #pragma unroll
        for (int oc = 0; oc < 2; ++oc) {
            int cl = 2 * t + oc;
            if (cl >= n_cl) continue;
            float* lss = oc ? loss1 : loss0;
            #pragma unroll
            for (int j = 0; j < K; ++j) {
                float cv = __expf(-acc[cl * K + j]);
                lss[j] = cv * (-__logf(1.f - cv + EPS));
            }
            if (oc) { msk1 = fmsk[cl]; have1 = true; }
            else    { msk0 = fmsk[cl]; have0 = true; }
        }
    }

    if (have0) {
        int slot0 = clause_batch[c_base + 2 * t] - g_lo;
        int slot1 = have1 ? (clause_batch[c_base + 2 * t + 1] - g_lo) : -1;
        if (have1 && slot1 == slot0) {
            #pragma unroll
            for (int j = 0; j < K; ++j) loss0[j] += loss1[j];
            msk0 &= msk1;
            have1 = false;
        }
        if (slot0 < MAXSLOT) {
            #pragma unroll
            for (int j = 0; j < K; ++j) atomicAdd(&pg[slot0 * K + j], loss0[j]);
            atomicAnd(&pmask[slot0], msk0);
        } else {
            #pragma unroll
            for (int j = 0; j < K; ++j) atomicAdd(&per_graph[(size_t)(g_lo + slot0) * K + j], loss0[j]);
            atomicAnd(&gmask[g_lo + slot0], msk0);
        }
        if (have1) {
            if (slot1 < MAXSLOT) {
                #pragma unroll
                for (int j = 0; j < K; ++j) atomicAdd(&pg[slot1 * K + j], loss1[j]);
                atomicAnd(&pmask[slot1], msk1);
            } else {
                #pragma unroll
                for (int j = 0; j < K; ++j) atomicAdd(&per_graph[(size_t)(g_lo + slot1) * K + j], loss1[j]);
                atomicAnd(&gmask[g_lo + slot1], msk1);
            }
        }
    }
    __syncthreads();

    const int nslots = min(sh_ghi - g_lo + 1, MAXSLOT);
    if (t < nslots * K) {
        int s = t >> 3, j = t & 7;
        atomicAdd(&per_graph[(size_t)(g_lo + s) * K + j], pg[s * K + j]);
    }
    if (t < nslots) atomicAnd(&gmask[g_lo + t], pmask[t]);
}

// ---------------- Final: per-graph sqrt, sort-8, cost dot, solved ------------
__global__ __launch_bounds__(256) void final_kernel(
    const float* __restrict__ per_graph, const unsigned* __restrict__ gmask,
    int n_graphs, float* __restrict__ out)
{
    const int t = threadIdx.x;
    float dot = 0.f;
    if (t < n_graphs) {
        float v[K];
        #pragma unroll
        for (int j = 0; j < K; ++j)
            v[j] = sqrtf(per_graph[(size_t)t * K + j] + SQRT_EPS) - sqrtf(SQRT_EPS);
        #pragma unroll
        for (int i = 1; i < K; ++i) {
            float key = v[i];
            int j = i - 1;
            while (j >= 0 && v[j] < key) { v[j + 1] = v[j]; --j; }
            v[j + 1] = key;
        }
        #pragma unroll
        for (int i = 0; i < K; ++i)
            dot = fmaf(v[i], (float)((i + 1) * (i + 1)), dot);
        out[1 + t] = (gmask[t] & 0xFFu) ? 1.f : 0.f;
    }
    __shared__ float red[256];
    red[t] = dot;
    __syncthreads();
    for (int s = 128; s >= 1; s >>= 1) {
        if (t < s) red[t] += red[t + s];
        __syncthreads();
    }
    if (t == 0) out[0] = red[0] * (1.f / 204.f);
}

// ---------------------------------------------------------------------------
extern "C" void kernel_launch(void* const* d_in, const int* in_sizes, int n_in,
                              void* d_out, int out_size, void* d_ws, size_t ws_size,
                              hipStream_t stream) {
    const float* x   = (const float*)d_in[0];
    const float* pol = (const float*)d_in[1];
    const int* vi    = (const int*)d_in[2];
    const int* ci    = (const int*)d_in[3];
    const int* cb    = (const int*)d_in[4];
    const float* W1  = (const float*)d_in[5];
    const float* b1  = (const float*)d_in[6];
    const float* W2  = (const float*)d_in[7];
    const float* b2  = (const float*)d_in[8];

    const int n_vars    = in_sizes[0] / DIM;
    const int n_edges   = in_sizes[1];
    const int n_clauses = in_sizes[4];
    const int n_graphs  = out_size - 1;
    const int nb        = (n_clauses + CB - 1) / CB;
    const int nt1       = (n_edges + TV1 - 1) / TV1;
    const int mlpB      = (n_vars + 255) / 256;

    // ---- workspace layout ----
    char* ws = (char*)d_ws;
    size_t off = 0;
    auto alloc = [&](size_t bytes) { char* p = ws + off; off += (bytes + 255) & ~(size_t)255; return p; };
    uint2*    lfp8   = (uint2*)alloc((size_t)n_vars * 8);
    unsigned* A      = (unsigned*)alloc((size_t)n_edges * 4);
    unsigned short* B1 = (unsigned short*)alloc((size_t)n_edges * 2);
    uint2*    B2     = (uint2*)alloc((size_t)n_edges * 8);
    unsigned* histV  = (unsigned*)alloc((size_t)NKV * NT1MAX * 4);
    unsigned* histB  = (unsigned*)alloc((size_t)NKC * NKV * MAXTV * 4);
    unsigned* histC  = (unsigned*)alloc((size_t)NKC * MAXTC * 64 * 4);
    unsigned* btotalV= (unsigned*)alloc((size_t)(NKV + 1) * 4);
    unsigned* baseV  = (unsigned*)alloc((size_t)(NKV + 1) * 4);
    unsigned* btotalB= (unsigned*)alloc((size_t)(NKC + 1) * 4);
    unsigned* baseB  = (unsigned*)alloc((size_t)(NKC + 1) * 4);
    float*    per_graph = (float*)alloc((size_t)n_graphs * K * 4);
    unsigned* gmask  = (unsigned*)alloc((size_t)n_graphs * 4);
    unsigned short* w1tg = (unsigned short*)alloc((size_t)DIM * DIM * 2);
    unsigned short* w2tg = (unsigned short*)alloc((size_t)16 * DIM * 2);

    hipMemsetAsync(histV, 0, (size_t)NKV * NT1MAX * 4, stream);
    hipMemsetAsync(histB, 0, (size_t)NKC * NKV * MAXTV * 4, stream);
    hipMemsetAsync(histC, 0, (size_t)NKC * MAXTC * 64 * 4, stream);
    hipMemsetAsync(per_graph, 0, (size_t)n_graphs * K * 4, stream);
    hipMemsetAsync(gmask, 0xFF, (size_t)n_graphs * 4, stream);

    prep_kernel<<<1, 512, 0, stream>>>(W1, W2, w1tg, w2tg);
    mlp_histV_kernel<<<mlpB + nt1, 512, 0, stream>>>(x, w1tg, b1, w2tg, b2,
                                                     lfp8, n_vars, vi, histV,
                                                     n_edges, mlpB);

    scanrowV_kernel<<<NKV, 256, 0, stream>>>(histV, btotalV);
    baseV_pub_kernel<<<1, 64, 0, stream>>>(btotalV, baseV);
    scatterV_kernel<<<nt1, 256, 0, stream>>>(ci, vi, pol, histV, btotalV, A, n_edges);

    histB_kernel<<<NKV * MAXTV, 256, 0, stream>>>(A, baseV, histB);
    scanrowB_kernel<<<NKC, 256, 0, stream>>>(histB, btotalB);
    baseB_pub_kernel<<<1, 64, 0, stream>>>(btotalB, baseB);
    scatterB_kernel<<<NKV * MAXTV, 256, 0, stream>>>(A, lfp8, baseV, histB, btotalB,
                                                     B1, B2, n_vars);

    histC_kernel<<<NKC * MAXTC, 256, 0, stream>>>(B1, baseB, histC);

    bucket_kernel<<<nb, 256, 0, stream>>>(B1, B2, baseB, histC, cb,
                                          per_graph, gmask, n_clauses, n_graphs);
    final_kernel<<<1, 256, 0, stream>>>(per_graph, gmask, n_graphs, (float*)d_out);
}

// Round 18
// 409.951 us; speedup vs baseline: 1.1888x; 1.0140x over previous
//
#include <hip/hip_runtime.h>
#include <hip/hip_bf16.h>

#define DIM 128
#define K 8
#define EPS 1e-8f
#define SQRT_EPS 1e-6f

#define CB 512           // clauses per fine bucket
#define CSHIFT 9
#define MAXSLOT 32       // graph slots per bucket
#define SARR_CAP 2560    // mean 1536, +26 sigma
#define MAXE 10          // SARR_CAP/256 register-staged edges per thread

// input tiles
#define TV1 8192
#define NT1MAX 1024
// v-level: 512 groups of 1024 vars
#define NKV 512
#define VSH 10
// attach/coarse-c level
#define TB 4096
#define MAXTV 4
#define NKC 64           // coarse clause groups (c>>15)
// fine-c level (virtual: counts only, no materialized sort)
#define TC 4096
#define MAXTC 32

typedef __attribute__((ext_vector_type(8))) short bf16x8;
typedef __attribute__((ext_vector_type(4))) float f32x4;

__device__ inline short bfc(float f) {
    union { __hip_bfloat16 h; short s; } u;
    u.h = __float2bfloat16(f);
    return u.s;
}

#define LDW 136
#define NW 8   // waves per mlp block

// ---------------- one-shot: transpose W1,W2 to bf16 in global ----------------
__global__ __launch_bounds__(512) void prep_kernel(
    const float* __restrict__ W1, const float* __restrict__ W2,
    unsigned short* __restrict__ w1tg, unsigned short* __restrict__ w2tg)
{
    const int t = threadIdx.x;
    for (int i = t; i < DIM * DIM; i += 512) {
        int r = i >> 7, c = i & 127;
        w1tg[c * DIM + r] = (unsigned short)bfc(W1[i]);
    }
    for (int i = t; i < 16 * DIM; i += 512) {
        int c = i >> 7, j = i & 127;
        w2tg[c * DIM + j] = (c < 8) ? (unsigned short)bfc(W2[j * 8 + c])
                                    : (unsigned short)0;
    }
}

// -------- fused: MLP (blocks < mlpB) || histV (blocks >= mlpB) ---------------
__global__ __launch_bounds__(512) void mlp_histV_kernel(
    const float* __restrict__ x, const unsigned short* __restrict__ w1tg,
    const float* __restrict__ b1, const unsigned short* __restrict__ w2tg,
    const float* __restrict__ b2, uint2* __restrict__ lfp8, int n_vars,
    const int* __restrict__ vi, unsigned* __restrict__ histV, int n_edges,
    int mlpB)
{
    __shared__ __align__(16) short w1t[DIM][LDW];       // 34816 B
    __shared__ __align__(16) short hlds[NW][16][LDW];   // 34816 B
    __shared__ __align__(16) float lout[NW][16][8];     //  4096 B
    __shared__ unsigned hl[NKV];                        //  2048 B

    const int t = threadIdx.x;

    if ((int)blockIdx.x >= mlpB) {
        const int b = (int)blockIdx.x - mlpB;
        for (int i = t; i < NKV; i += 512) hl[i] = 0u;
        __syncthreads();
        const int e0 = b * TV1, e1 = min(e0 + TV1, n_edges);
        for (int e = e0 + t; e < e1; e += 512)
            atomicAdd(&hl[((unsigned)vi[e]) >> VSH], 1u);
        __syncthreads();
        for (int i = t; i < NKV; i += 512) histV[(size_t)i * NT1MAX + b] = hl[i];
        return;
    }

    const int wave = t >> 6, lane = t & 63;
    const int lr = lane & 15, lg = lane >> 4;

    for (int i = t; i < DIM * DIM / 8; i += 512) {
        int row = i >> 4, col8 = (i & 15) * 8;
        *(bf16x8*)&w1t[row][col8] = *(const bf16x8*)&w1tg[row * DIM + col8];
    }
    __syncthreads();

    const int rbase = blockIdx.x * 256 + wave * 32;

    bf16x8 a[2][4];
    #pragma unroll
    for (int rt = 0; rt < 2; ++rt) {
        int row = rbase + rt * 16 + lr;
        bool ok = row < n_vars;
        const float* xp = x + (size_t)row * DIM + lg * 8;
        #pragma unroll
        for (int kt = 0; kt < 4; ++kt) {
            bf16x8 av = {0,0,0,0,0,0,0,0};
            if (ok) {
                float4 f0 = *(const float4*)(xp + kt * 32);
                float4 f1 = *(const float4*)(xp + kt * 32 + 4);
                av[0]=bfc(f0.x); av[1]=bfc(f0.y); av[2]=bfc(f0.z); av[3]=bfc(f0.w);
                av[4]=bfc(f1.x); av[5]=bfc(f1.y); av[6]=bfc(f1.z); av[7]=bfc(f1.w);
            }
            a[rt][kt] = av;
        }
    }

    bf16x8 bb[4];
    #pragma unroll
    for (int kt = 0; kt < 4; ++kt)
        bb[kt] = *(const bf16x8*)&w2tg[lr * DIM + kt * 32 + lg * 8];
    float b2v = (lr < 8) ? b2[lr] : 0.f;

    #pragma unroll
    for (int rt = 0; rt < 2; ++rt) {
        #pragma unroll
        for (int n = 0; n < 8; ++n) {
            f32x4 acc = {0.f, 0.f, 0.f, 0.f};
            #pragma unroll
            for (int kt = 0; kt < 4; ++kt) {
                bf16x8 bf = *(const bf16x8*)&w1t[n * 16 + lr][kt * 32 + lg * 8];
                acc = __builtin_amdgcn_mfma_f32_16x16x32_bf16(a[rt][kt], bf, acc, 0, 0, 0);
            }
            float bcol = b1[n * 16 + lr];
            #pragma unroll
            for (int r = 0; r < 4; ++r) {
                float h = fmaxf(acc[r] + bcol, 0.f);
                hlds[wave][lg * 4 + r][n * 16 + lr] = bfc(h);
            }
        }
        f32x4 acc2 = {0.f, 0.f, 0.f, 0.f};
        #pragma unroll
        for (int kt = 0; kt < 4; ++kt) {
            bf16x8 af = *(const bf16x8*)&hlds[wave][lr][kt * 32 + lg * 8];
            acc2 = __builtin_amdgcn_mfma_f32_16x16x32_bf16(af, bb[kt], acc2, 0, 0, 0);
        }
        if (lr < 8) {
            #pragma unroll
            for (int r = 0; r < 4; ++r)
                lout[wave][lg * 4 + r][lr] = acc2[r] + b2v;
        }
        if (lane < 16) {
            int row = rbase + rt * 16 + lane;
            if (row < n_vars) {
                const float* f = lout[wave][lane];
                unsigned lo = 0u, hi = 0u;
                lo = __builtin_amdgcn_cvt_pk_fp8_f32(f[0], f[1], lo, false);
                lo = __builtin_amdgcn_cvt_pk_fp8_f32(f[2], f[3], lo, true);
                hi = __builtin_amdgcn_cvt_pk_fp8_f32(f[4], f[5], hi, false);
                hi = __builtin_amdgcn_cvt_pk_fp8_f32(f[6], f[7], hi, true);
                lfp8[row] = make_uint2(lo, hi);
            }
        }
    }
}

// exclusive scan each row (width NT1MAX=1024) over tiles
__global__ __launch_bounds__(256) void scanrowV_kernel(
    unsigned* __restrict__ hist, unsigned* __restrict__ btotal)
{
    const int t = threadIdx.x;
    const size_t base = (size_t)blockIdx.x * NT1MAX + t * 4;
    uint4 v = *(const uint4*)(hist + base);
    unsigned pre0 = 0, pre1 = v.x, pre2 = v.x + v.y, pre3 = v.x + v.y + v.z;
    unsigned run = pre3 + v.w;
    __shared__ unsigned ts[256];
    ts[t] = run;
    __syncthreads();
    for (int off = 1; off < 256; off <<= 1) {
        unsigned xv = (t >= off) ? ts[t - off] : 0u;
        __syncthreads();
        ts[t] += xv;
        __syncthreads();
    }
    unsigned ex = ts[t] - run;
    uint4 o = {ex + pre0, ex + pre1, ex + pre2, ex + pre3};
    *(uint4*)(hist + base) = o;
    if (t == 255) btotal[blockIdx.x] = ts[255];
}

// staged scatter into v-group order; payload u32 = voff<<22 | neg<<21 | c
__global__ __launch_bounds__(256) void scatterV_kernel(
    const int* __restrict__ ci, const int* __restrict__ vi,
    const float* __restrict__ pol, const unsigned* __restrict__ histV,
    const unsigned* __restrict__ btotalV, unsigned* __restrict__ A, int n_edges)
{
    __shared__ unsigned sa[TV1];            // 32 KB
    __shared__ unsigned short bmap[TV1];    // 16 KB
    __shared__ unsigned h[NKV], lst[NKV], h2[NKV], gst[NKV];  // 8 KB
    __shared__ unsigned baseVl[NKV];        //  2 KB
    __shared__ unsigned ts[256];
    const int t = threadIdx.x, b = blockIdx.x;

    {
        unsigned v0 = btotalV[2 * t], v1 = btotalV[2 * t + 1];
        unsigned run = v0 + v1;
        ts[t] = run;
        __syncthreads();
        for (int off = 1; off < 256; off <<= 1) {
            unsigned xv = (t >= off) ? ts[t - off] : 0u;
            __syncthreads();
            ts[t] += xv;
            __syncthreads();
        }
        unsigned ex = ts[t] - run;
        baseVl[2 * t] = ex; baseVl[2 * t + 1] = ex + v0;
    }
    for (int i = t; i < NKV; i += 256) h[i] = 0u;
    __syncthreads();
    const int e0 = b * TV1, e1 = min(e0 + TV1, n_edges), n = e1 - e0;
    for (int e = e0 + t; e < e1; e += 256)
        atomicAdd(&h[((unsigned)vi[e]) >> VSH], 1u);
    __syncthreads();
    unsigned a0 = h[2 * t], a1 = h[2 * t + 1];
    unsigned run = a0 + a1;
    ts[t] = run;
    __syncthreads();
    for (int off = 1; off < 256; off <<= 1) {
        unsigned xv = (t >= off) ? ts[t - off] : 0u;
        __syncthreads();
        ts[t] += xv;
        __syncthreads();
    }
    unsigned ex = ts[t] - run;
    lst[2 * t] = ex; lst[2 * t + 1] = ex + a0;
    h2[2 * t] = ex;  h2[2 * t + 1] = ex + a0;
    __syncthreads();
    for (int e = e0 + t; e < e1; e += 256) {
        unsigned c = (unsigned)ci[e];
        unsigned v = (unsigned)vi[e];
        unsigned neg = (pol[e] < 0.f) ? 1u : 0u;
        unsigned k = v >> VSH;
        unsigned p = atomicAdd(&h2[k], 1u);
        sa[p] = c | (neg << 21) | ((v & ((1u << VSH) - 1u)) << 22);
        bmap[p] = (unsigned short)k;
    }
    for (int i = t; i < NKV; i += 256)
        gst[i] = baseVl[i] + histV[(size_t)i * NT1MAX + b];
    __syncthreads();
    for (int s = t; s < n; s += 256) {
        unsigned k = bmap[s];
        A[gst[k] + (s - lst[k])] = sa[s];
    }
}

// ================= level B: attach sign-applied logits + coarse-c partition ==

__global__ __launch_bounds__(256) void histB_kernel(
    const unsigned* __restrict__ A, const unsigned* __restrict__ baseV,
    unsigned* __restrict__ histB)
{
    __shared__ unsigned h[NKC];
    const int t = threadIdx.x;
    const int vg = blockIdx.x / MAXTV, i = blockIdx.x % MAXTV;
    const unsigned slo = baseV[vg], shi = baseV[vg + 1];
    const unsigned t0 = slo + (unsigned)i * TB;
    if (t0 >= shi) return;
    const unsigned t1 = min(t0 + TB, shi);
    if (t < NKC) h[t] = 0u;
    __syncthreads();
    for (unsigned e = t0 + t; e < t1; e += 256)
        atomicAdd(&h[(A[e] & 0x1FFFFFu) >> 15], 1u);
    __syncthreads();
    if (t < NKC) histB[(size_t)t * (NKV * MAXTV) + blockIdx.x] = h[t];
}

__global__ void baseV_pub_kernel(const unsigned* __restrict__ tv,
                                 unsigned* __restrict__ bv)
{
    if (threadIdx.x == 0) {
        unsigned r = 0;
        for (int k = 0; k < NKV; ++k) { bv[k] = r; r += tv[k]; }
        bv[NKV] = r;
    }
}

// exclusive scan each row (width NKV*MAXTV = 2048) over tiles
__global__ __launch_bounds__(256) void scanrowB_kernel(
    unsigned* __restrict__ hist, unsigned* __restrict__ btotal)
{
    const int t = threadIdx.x;
    const size_t base = (size_t)blockIdx.x * (NKV * MAXTV) + t * 8;
    uint4 v0 = *(const uint4*)(hist + base);
    uint4 v1 = *(const uint4*)(hist + base + 4);
    unsigned p0 = 0, p1 = v0.x, p2 = p1 + v0.y, p3 = p2 + v0.z, p4 = p3 + v0.w;
    unsigned p5 = p4 + v1.x, p6 = p5 + v1.y, p7 = p6 + v1.z;
    unsigned run = p7 + v1.w;
    __shared__ unsigned ts[256];
    ts[t] = run;
    __syncthreads();
    for (int off = 1; off < 256; off <<= 1) {
        unsigned xv = (t >= off) ? ts[t - off] : 0u;
        __syncthreads();
        ts[t] += xv;
        __syncthreads();
    }
    unsigned ex = ts[t] - run;
    uint4 o0 = {ex + p0, ex + p1, ex + p2, ex + p3};
    uint4 o1 = {ex + p4, ex + p5, ex + p6, ex + p7};
    *(uint4*)(hist + base) = o0;
    *(uint4*)(hist + base + 4) = o1;
    if (t == 255) btotal[blockIdx.x] = ts[255];
}

__global__ void baseB_pub_kernel(const unsigned* __restrict__ tb,
                                 unsigned* __restrict__ bb)
{
    if (threadIdx.x == 0) {
        unsigned r = 0;
        for (int k = 0; k < NKC; ++k) { bb[k] = r; r += tb[k]; }
        bb[NKC] = r;
    }
}

// attach: LDS logit slice + SIGN-APPLY + scatter (baseB scanned in prologue)
__global__ __launch_bounds__(256) void scatterB_kernel(
    const unsigned* __restrict__ A, const uint2* __restrict__ lfp8,
    const unsigned* __restrict__ baseV, const unsigned* __restrict__ histB,
    const unsigned* __restrict__ btotalB, unsigned short* __restrict__ B1,
    uint2* __restrict__ B2, int n_vars)
{
    __shared__ uint2 slice[1 << VSH];       //  8 KB
    __shared__ unsigned short st1[TB];      //  8 KB
    __shared__ uint2 st2[TB];               // 32 KB
    __shared__ unsigned char bmap[TB];      //  4 KB
    __shared__ unsigned h[NKC], lst[NKC], h2[NKC], gst[NKC], baseBl[NKC];
    const int t = threadIdx.x;
    const int vg = blockIdx.x / MAXTV, i = blockIdx.x % MAXTV;
    const unsigned slo = baseV[vg], shi = baseV[vg + 1];
    const unsigned t0 = slo + (unsigned)i * TB;
    if (t0 >= shi) return;
    const unsigned t1 = min(t0 + TB, shi);
    const int n = (int)(t1 - t0);
    if (t < NKC) h[t] = btotalB[t];
    __syncthreads();
    if (t == 0) {
        unsigned r = 0;
        for (int k = 0; k < NKC; ++k) { baseBl[k] = r; r += h[k]; }
    }
    __syncthreads();
    for (int s = t; s < (1 << VSH); s += 256) {
        int v = (vg << VSH) + s;
        slice[s] = (v < n_vars) ? lfp8[v] : make_uint2(0u, 0u);
    }
    if (t < NKC) h[t] = 0u;
    __syncthreads();
    for (unsigned e = t0 + t; e < t1; e += 256)
        atomicAdd(&h[(A[e] & 0x1FFFFFu) >> 15], 1u);
    __syncthreads();
    if (t == 0) {
        unsigned r = 0;
        for (int k = 0; k < NKC; ++k) { lst[k] = r; h2[k] = r; r += h[k]; }
    }
    __syncthreads();
    for (unsigned e = t0 + t; e < t1; e += 256) {
        unsigned a = A[e];
        unsigned c = a & 0x1FFFFFu;
        unsigned k = c >> 15;
        unsigned p = atomicAdd(&h2[k], 1u);
        uint2 g = slice[a >> 22];
        unsigned sm = ((a >> 21) & 1u) * 0x80808080u;
        g.x ^= sm; g.y ^= sm;
        st1[p] = (unsigned short)(c & 0x7FFFu);
        st2[p] = g;
        bmap[p] = (unsigned char)k;
    }
    if (t < NKC) gst[t] = baseBl[t] + histB[(size_t)t * (NKV * MAXTV) + blockIdx.x];
    __syncthreads();
    for (int s = t; s < n; s += 256) {
        unsigned k = bmap[s];
        unsigned pos = gst[k] + (s - lst[k]);
        B1[pos] = st1[s];
        B2[pos] = st2[s];
    }
}

// --------- histC: raw per-(segment,tile) fine-bin counts, tile-major ---------
__global__ __launch_bounds__(256) void histC_kernel(
    const unsigned short* __restrict__ B1, const unsigned* __restrict__ baseB,
    unsigned* __restrict__ histC)
{
    __shared__ unsigned h[64];
    const int t = threadIdx.x;
    const int k1 = blockIdx.x / MAXTC, i = blockIdx.x % MAXTC;
    const unsigned slo = baseB[k1], shi = baseB[k1 + 1];
    const unsigned t0 = slo + (unsigned)i * TC;
    if (t0 >= shi) return;
    const unsigned t1 = min(t0 + TC, shi);
    if (t < 64) h[t] = 0u;
    __syncthreads();
    for (unsigned e = t0 + t; e < t1; e += 256)
        atomicAdd(&h[((unsigned)B1[e] >> 9) & 63u], 1u);
    __syncthreads();
    if (t < 64) histC[((size_t)(k1 * MAXTC + i)) * 64 + t] = h[t];
}

// --- bucket: tile-run gather + counting-sort + owner-reduce + fused fold -----
// hrow (8 KB) aliases sarrL: consumed entirely in prologue before any sarrL write.
__global__ __launch_bounds__(256) void bucket_kernel(
    const unsigned short* __restrict__ B1, const uint2* __restrict__ B2,
    const unsigned* __restrict__ baseB, const unsigned* __restrict__ histC,
    const int* __restrict__ clause_batch,
    float* __restrict__ per_graph, unsigned* __restrict__ gmask,
    int n_clauses, int n_graphs)
{
    __shared__ uint2 sarrL[SARR_CAP];   // 20 KB (aliases hrow in prologue, acc in fallback)
    __shared__ unsigned runstart[MAXTC];
    __shared__ unsigned runpre[MAXTC + 1];
    __shared__ unsigned cnt[CB];        //  2 KB
    __shared__ unsigned cst[CB + 1];    //  2 KB
    __shared__ float sp[256];           //  1 KB
    __shared__ float pg[MAXSLOT * K];   //  1 KB
    __shared__ unsigned pmask[MAXSLOT];
    __shared__ unsigned wtot[4];
    __shared__ int sh_ghi;

    unsigned* hrow = (unsigned*)sarrL;  // 8 KB alias, prologue-only

    const int t = threadIdx.x;
    const int lane = t & 63, wv = t >> 6;
    const int bkt = blockIdx.x;
    const int k1 = bkt >> 6, f = bkt & 63;
    const int c_base = bkt << CSHIFT;
    const int n_cl = min(CB, n_clauses - c_base);
    const int g_lo = clause_batch[c_base];

    {
        float v = __builtin_amdgcn_cvt_f32_fp8((unsigned)t, 0);
        sp[t] = fmaxf(v, 0.f) + __logf(1.f + __expf(-fabsf(v)));
    }
    for (int i = t; i < CB; i += 256) cnt[i] = 0u;
    for (int i = t; i < MAXSLOT * K; i += 256) pg[i] = 0.f;
    if (t < MAXSLOT) pmask[t] = 0xFFu;
    if (t == 0) sh_ghi = clause_batch[c_base + n_cl - 1];

    // load raw counts for this coarse segment (tile-major rows, coalesced)
    for (int i = t; i < MAXTC * 64; i += 256)
        hrow[i] = histC[((size_t)(k1 * MAXTC)) * 64 + i];
    __syncthreads();

    // per-tile run offset (prefix over bins < f) and length; wave-0 scan
    const unsigned slo = baseB[k1];
    if (t < MAXTC) {
        unsigned off = 0;
        for (int fp = 0; fp < f; ++fp) off += hrow[t * 64 + fp];
        unsigned len = hrow[t * 64 + f];
        runstart[t] = slo + (unsigned)t * TC + off;
        unsigned incl = len;
        #pragma unroll
        for (int o = 1; o < 32; o <<= 1) {
            unsigned v = __shfl_up(incl, o, 64);
            if (lane >= o) incl += v;
        }
        runpre[t + 1] = incl;
        if (t == 0) runpre[0] = 0;
    }
    __syncthreads();   // hrow dead after this barrier; sarrL free to use
    const int ne = (int)runpre[MAXTC];

    float loss0[K], loss1[K];
    unsigned msk0 = 0u, msk1 = 0u;
    bool have0 = false, have1 = false;

    if (ne <= SARR_CAP) {
        // ---- register staging with run-table address translation ----
        unsigned short myS[MAXE];
        uint2 myL[MAXE];
        #pragma unroll
        for (int u = 0; u < MAXE; ++u) {
            int e = t + 256 * u;
            if (e < ne) {
                int lo2 = 0, hi2 = MAXTC;
                while (lo2 + 1 < hi2) {
                    int mid = (lo2 + hi2) >> 1;
                    if (runpre[mid] <= (unsigned)e) lo2 = mid; else hi2 = mid;
                }
                unsigned pos = runstart[lo2] + ((unsigned)e - runpre[lo2]);
                myS[u] = (unsigned short)(B1[pos] & 511u);
                myL[u] = B2[pos];
                atomicAdd(&cnt[myS[u]], 1u);
            } else {
                myS[u] = (unsigned short)0xFFFFu;
                myL[u] = make_uint2(0u, 0u);
            }
        }
        __syncthreads();
        unsigned a0 = cnt[2 * t], a1 = cnt[2 * t + 1];
        unsigned run = a0 + a1;
        unsigned incl = run;
        #pragma unroll
        for (int off = 1; off < 64; off <<= 1) {
            unsigned v = __shfl_up(incl, off, 64);
            if (lane >= off) incl += v;
        }
        if (lane == 63) wtot[wv] = incl;
        __syncthreads();
        unsigned wpre = 0;
        #pragma unroll
        for (int w = 0; w < 3; ++w) if (w < wv) wpre += wtot[w];
        unsigned ex = wpre + incl - run;
        cst[2 * t] = ex; cst[2 * t + 1] = ex + a0;
        cnt[2 * t] = ex; cnt[2 * t + 1] = ex + a0;
        if (t == 255) cst[CB] = ex + run;
        __syncthreads();
        #pragma unroll
        for (int u = 0; u < MAXE; ++u) {
            if (myS[u] != (unsigned short)0xFFFFu) {
                unsigned p = atomicAdd(&cnt[myS[u]], 1u);
                sarrL[p] = myL[u];
            }
        }
        __syncthreads();
        #pragma unroll
        for (int oc = 0; oc < 2; ++oc) {
            int cl = 2 * t + oc;
            if (cl >= n_cl) continue;
            unsigned s0 = cst[cl];
            int n = (int)(cst[cl + 1] - s0);
            float sums[K] = {0.f, 0.f, 0.f, 0.f, 0.f, 0.f, 0.f, 0.f};
            unsigned ormask = 0u;
            for (int base = 0; base < n; base += 8) {
                int m = min(8, n - base);
                uint2 gs[8];
                for (int i2 = 0; i2 < m; ++i2) gs[i2] = sarrL[s0 + base + i2];
                for (int i2 = 0; i2 < m; ++i2) {
                    #pragma unroll
                    for (int j = 0; j < 4; ++j) {
                        unsigned b0 = (gs[i2].x >> (8 * j)) & 0xFFu;
                        unsigned b1 = (gs[i2].y >> (8 * j)) & 0xFFu;
                        sums[j]     += sp[b0];
                        sums[j + 4] += sp[b1];
                        ormask |= (b0 - 1u < 0x7Fu) ? (1u << j) : 0u;
                        ormask |= (b1 - 1u < 0x7Fu) ? (1u << (j + 4)) : 0u;
                    }
                }
            }
            float* lss = oc ? loss1 : loss0;
            #pragma unroll
            for (int j = 0; j < K; ++j) {
                float cv = __expf(-sums[j]);
                lss[j] = cv * (-__logf(1.f - cv + EPS));
            }
            if (oc) { msk1 = ormask; have1 = true; }
            else    { msk0 = ormask; have0 = true; }
        }
    } else {
        // ---- fallback: LDS-atomic accumulate with run translation ----
        float* acc = (float*)sarrL;        // 16 KB alias
        unsigned* fmsk = cnt;
        for (int i = t; i < CB * K; i += 256) acc[i] = 0.f;
        for (int i = t; i < CB; i += 256) fmsk[i] = 0u;
        __syncthreads();
        for (int e = t; e < ne; e += 256) {
            int lo2 = 0, hi2 = MAXTC;
            while (lo2 + 1 < hi2) {
                int mid = (lo2 + hi2) >> 1;
                if (runpre[mid] <= (unsigned)e) lo2 = mid; else hi2 = mid;
            }
            unsigned pos = runstart[lo2] + ((unsigned)e - runpre[lo2]);
            unsigned cl = B1[pos] & 511u;
            uint2 g = B2[pos];
            unsigned gt0 = 0u;
            #pragma unroll
            for (int j = 0; j < 4; ++j) {
                unsigned b0 = (g.x >> (8 * j)) & 0xFFu;
                unsigned b1 = (g.y >> (8 * j)) & 0xFFu;
                atomicAdd(&acc[cl * K + j], sp[b0]);
                atomicAdd(&acc[cl * K + j + 4], sp[b1]);
                gt0 |= (b0 - 1u < 0x7Fu) ? (1u << j) : 0u;
                gt0 |= (b1 - 1u < 0x7Fu) ? (1u << (j + 4)) : 0u;
            }
            atomicOr(&fmsk[cl], gt0);
        }
        __syncthreads();
        #pragma unroll
        for (int oc = 0; oc < 2; ++oc) {
            int cl = 2 * t + oc;
            if (cl >= n_cl) continue;
            float* lss = oc ? loss1 : loss0;
            #pragma unroll
            for (int j = 0; j < K; ++j) {
                float cv = __expf(-acc[cl * K + j]);
                lss[j] = cv * (-__logf(1.f - cv + EPS));
            }
            if (oc) { msk1 = fmsk[cl]; have1 = true; }
            else    { msk0 = fmsk[cl]; have0 = true; }
        }
    }

    if (have0) {
        int slot0 = clause_batch[c_base + 2 * t] - g_lo;
        int slot1 = have1 ? (clause_batch[c_base + 2 * t + 1] - g_lo) : -1;
        if (have1 && slot1 == slot0) {
            #pragma unroll
            for (int j = 0; j < K; ++j) loss0[j] += loss1[j];
            msk0 &= msk1;
            have1 = false;
        }
        if (slot0 < MAXSLOT) {
            #pragma unroll
            for (int j = 0; j < K; ++j) atomicAdd(&pg[slot0 * K + j], loss0[j]);
            atomicAnd(&pmask[slot0], msk0);
        } else {
            #pragma unroll
            for (int j = 0; j < K; ++j) atomicAdd(&per_graph[(size_t)(g_lo + slot0) * K + j], loss0[j]);
            atomicAnd(&gmask[g_lo + slot0], msk0);
        }
        if (have1) {
            if (slot1 < MAXSLOT) {
                #pragma unroll
                for (int j = 0; j < K; ++j) atomicAdd(&pg[slot1 * K + j], loss1[j]);
                atomicAnd(&pmask[slot1], msk1);
            } else {
                #pragma unroll
                for (int j = 0; j < K; ++j) atomicAdd(&per_graph[(size_t)(g_lo + slot1) * K + j], loss1[j]);
                atomicAnd(&gmask[g_lo + slot1], msk1);
            }
        }
    }
    __syncthreads();

    const int nslots = min(sh_ghi - g_lo + 1, MAXSLOT);
    if (t < nslots * K) {
        int s = t >> 3, j = t & 7;
        atomicAdd(&per_graph[(size_t)(g_lo + s) * K + j], pg[s * K + j]);
    }
    if (t < nslots) atomicAnd(&gmask[g_lo + t], pmask[t]);
}

// ---------------- Final: per-graph sqrt, sort-8, cost dot, solved ------------
__global__ __launch_bounds__(256) void final_kernel(
    const float* __restrict__ per_graph, const unsigned* __restrict__ gmask,
    int n_graphs, float* __restrict__ out)
{
    const int t = threadIdx.x;
    float dot = 0.f;
    if (t < n_graphs) {
        float v[K];
        #pragma unroll
        for (int j = 0; j < K; ++j)
            v[j] = sqrtf(per_graph[(size_t)t * K + j] + SQRT_EPS) - sqrtf(SQRT_EPS);
        #pragma unroll
        for (int i = 1; i < K; ++i) {
            float key = v[i];
            int j = i - 1;
            while (j >= 0 && v[j] < key) { v[j + 1] = v[j]; --j; }
            v[j + 1] = key;
        }
        #pragma unroll
        for (int i = 0; i < K; ++i)
            dot = fmaf(v[i], (float)((i + 1) * (i + 1)), dot);
        out[1 + t] = (gmask[t] & 0xFFu) ? 1.f : 0.f;
    }
    __shared__ float red[256];
    red[t] = dot;
    __syncthreads();
    for (int s = 128; s >= 1; s >>= 1) {
        if (t < s) red[t] += red[t + s];
        __syncthreads();
    }
    if (t == 0) out[0] = red[0] * (1.f / 204.f);
}

// ---------------------------------------------------------------------------
extern "C" void kernel_launch(void* const* d_in, const int* in_sizes, int n_in,
                              void* d_out, int out_size, void* d_ws, size_t ws_size,
                              hipStream_t stream) {
    const float* x   = (const float*)d_in[0];
    const float* pol = (const float*)d_in[1];
    const int* vi    = (const int*)d_in[2];
    const int* ci    = (const int*)d_in[3];
    const int* cb    = (const int*)d_in[4];
    const float* W1  = (const float*)d_in[5];
    const float* b1  = (const float*)d_in[6];
    const float* W2  = (const float*)d_in[7];
    const float* b2  = (const float*)d_in[8];

    const int n_vars    = in_sizes[0] / DIM;
    const int n_edges   = in_sizes[1];
    const int n_clauses = in_sizes[4];
    const int n_graphs  = out_size - 1;
    const int nb        = (n_clauses + CB - 1) / CB;
    const int nt1       = (n_edges + TV1 - 1) / TV1;
    const int mlpB      = (n_vars + 255) / 256;

    // ---- workspace layout ----
    char* ws = (char*)d_ws;
    size_t off = 0;
    auto alloc = [&](size_t bytes) { char* p = ws + off; off += (bytes + 255) & ~(size_t)255; return p; };
    uint2*    lfp8   = (uint2*)alloc((size_t)n_vars * 8);
    unsigned* A      = (unsigned*)alloc((size_t)n_edges * 4);
    unsigned short* B1 = (unsigned short*)alloc((size_t)n_edges * 2);
    uint2*    B2     = (uint2*)alloc((size_t)n_edges * 8);
    unsigned* histV  = (unsigned*)alloc((size_t)NKV * NT1MAX * 4);
    unsigned* histB  = (unsigned*)alloc((size_t)NKC * NKV * MAXTV * 4);
    unsigned* histC  = (unsigned*)alloc((size_t)NKC * MAXTC * 64 * 4);
    unsigned* btotalV= (unsigned*)alloc((size_t)(NKV + 1) * 4);
    unsigned* baseV  = (unsigned*)alloc((size_t)(NKV + 1) * 4);
    unsigned* btotalB= (unsigned*)alloc((size_t)(NKC + 1) * 4);
    unsigned* baseB  = (unsigned*)alloc((size_t)(NKC + 1) * 4);
    float*    per_graph = (float*)alloc((size_t)n_graphs * K * 4);
    unsigned* gmask  = (unsigned*)alloc((size_t)n_graphs * 4);
    unsigned short* w1tg = (unsigned short*)alloc((size_t)DIM * DIM * 2);
    unsigned short* w2tg = (unsigned short*)alloc((size_t)16 * DIM * 2);

    hipMemsetAsync(histV, 0, (size_t)NKV * NT1MAX * 4, stream);
    hipMemsetAsync(histB, 0, (size_t)NKC * NKV * MAXTV * 4, stream);
    hipMemsetAsync(histC, 0, (size_t)NKC * MAXTC * 64 * 4, stream);
    hipMemsetAsync(per_graph, 0, (size_t)n_graphs * K * 4, stream);
    hipMemsetAsync(gmask, 0xFF, (size_t)n_graphs * 4, stream);

    prep_kernel<<<1, 512, 0, stream>>>(W1, W2, w1tg, w2tg);
    mlp_histV_kernel<<<mlpB + nt1, 512, 0, stream>>>(x, w1tg, b1, w2tg, b2,
                                                     lfp8, n_vars, vi, histV,
                                                     n_edges, mlpB);

    scanrowV_kernel<<<NKV, 256, 0, stream>>>(histV, btotalV);
    baseV_pub_kernel<<<1, 64, 0, stream>>>(btotalV, baseV);
    scatterV_kernel<<<nt1, 256, 0, stream>>>(ci, vi, pol, histV, btotalV, A, n_edges);

    histB_kernel<<<NKV * MAXTV, 256, 0, stream>>>(A, baseV, histB);
    scanrowB_kernel<<<NKC, 256, 0, stream>>>(histB, btotalB);
    baseB_pub_kernel<<<1, 64, 0, stream>>>(btotalB, baseB);
    scatterB_kernel<<<NKV * MAXTV, 256, 0, stream>>>(A, lfp8, baseV, histB, btotalB,
                                                     B1, B2, n_vars);

    histC_kernel<<<NKC * MAXTC, 256, 0, stream>>>(B1, baseB, histC);

    bucket_kernel<<<nb, 256, 0, stream>>>(B1, B2, baseB, histC, cb,
                                          per_graph, gmask, n_clauses, n_graphs);
    final_kernel<<<1, 256, 0, stream>>>(per_graph, gmask, n_graphs, (float*)d_out);
}